// Round 1
// baseline (273.942 us; speedup 1.0000x reference)
//
#include <hip/hip_runtime.h>

// ---------------------------------------------------------------------------
// HieraWeatherEmbedding R8: R7 + (a) outg2 XOR chunk swizzle keyed on
// (row>>3)&7 — kills the 16-way bank conflict on C3 G-GEMM B-frag reads
// (lane stride = 8 rows = 2176 B == 0 mod 128 B); (b) phase-B Fws register
// double-buffer prefetch — the runtime-S kt loop serialized ~38 L2 round
// trips per wave; now task i+1's <=6 fragment loads issue before task i's
// MFMAs (full 12-way unroll keeps indices compile-time, no scratch).
// fp32 I/O, bf16 fragments, fp32 accumulate.
// ---------------------------------------------------------------------------

typedef __attribute__((ext_vector_type(8))) short short8;
typedef __attribute__((ext_vector_type(4))) float f32x4;

__constant__ int GOFF[13] = {0,7,14,21,28,35,44,53,62,71,80,97,103};
__constant__ int K5A[12]  = {35,35,35,35,35,45,45,45,45,45,85,30};
__constant__ int SLOTS3[12] = {3,3,3,3,3,3,3,3,3,3,6,2};
__constant__ int FOFFA[12] = {0,3,6,9,12,15,18,21,24,27,30,36};   // slot offsets (total 38)
__constant__ int EOFF0[7] = {0,560,1120,1680,2240,2800,3520};
__constant__ int EOFF1[7] = {0,720,1440,2160,2880,4240,4720};
__constant__ int GSLOT[103] = {
  3,8,13,18,23,28,33,
  4,9,14,19,24,29,34,
  2,7,12,17,22,27,32,
  1,6,11,16,21,26,31,
  0,5,10,15,20,25,30,
  3,8,13,18,23,28,33,38,43,
  4,9,14,19,24,29,34,39,44,
  2,7,12,17,22,27,32,37,42,
  1,6,11,16,21,26,31,36,41,
  0,5,10,15,20,25,30,35,40,
  45,46,47,48,49,50,51,52,53,54,55,56,57,58,59,60,61,
  62,63,64,65,66,67};
__constant__ int GIDX[103] = {
  0,0,0,0,0,0,0, 1,1,1,1,1,1,1, 2,2,2,2,2,2,2, 3,3,3,3,3,3,3, 4,4,4,4,4,4,4,
  5,5,5,5,5,5,5,5,5, 6,6,6,6,6,6,6,6,6, 7,7,7,7,7,7,7,7,7, 8,8,8,8,8,8,8,8,8,
  9,9,9,9,9,9,9,9,9,
  10,10,10,10,10,10,10,10,10,10,10,10,10,10,10,10,10,
  11,11,11,11,11,11};

// fp32 workspace region (float offsets)
#define QK_GRP 0        // [12][2][128]
#define QK_ENS 3072     // [24][128]
#define QB_GRP 6144     // [12][2]
#define QB_ENS 6176     // [24]
#define CGRP   6208     // [12][128]
#define CENS   7744     // [128]
// byte offsets
#define CWQ_BYTE   43776    // float [103][2][8]
#define MPL_BYTE   50432    // float [12][128][256]   (1572864 B)
#define MEB_BYTE   1623296  // ushort [8mt][8kt][64][8] (65536 B)
#define QKEB_BYTE  1688832  // ushort [2nt][4kt][64][8] (8192 B)
#define FWS_BYTE   1697024  // ushort 304 frags * 512  (311296 B)

__device__ __forceinline__ float bf2f(unsigned short s) {
  return __uint_as_float(((unsigned)s) << 16);
}
__device__ __forceinline__ unsigned short f2bf(float f) {
  unsigned u = __float_as_uint(f);
  u += 0x7fffu + ((u >> 16) & 1u);
  return (unsigned short)(u >> 16);
}

// ---------------------------------------------------------------------------
// P1: QK/QB direct (two-phase in-block), CGRP, CENS, Mplain, MeB, F-zero.
// Grid 2204 x 256.
// ---------------------------------------------------------------------------
__global__ void hwe_p1(const float* __restrict__ giw, const float* __restrict__ gib,
                       const float* __restrict__ gow, const float* __restrict__ gob,
                       const float* __restrict__ cq,  const float* __restrict__ eq,
                       const float* __restrict__ eiw, const float* __restrict__ eib,
                       const float* __restrict__ eow, const float* __restrict__ eob,
                       float* __restrict__ wsf, float* __restrict__ Mplain,
                       unsigned short* __restrict__ MeB, unsigned short* __restrict__ Fws) {
  int blk = blockIdx.x, tid = threadIdx.x;
  int wave = tid >> 6, lane = tid & 63;
  if (blk < 48) {                        // QK + QB for (i,h) grp / (t,h) ens
    __shared__ float qf[64];
    bool ens = blk >= 24;
    int bi = ens ? blk - 24 : blk;
    int i = bi >> 1, h = bi & 1;
    const float* W  = ens ? eiw : giw + i*49152;   // [384][128]
    const float* bv = ens ? eib : gib + i*384;     // [384]
    const float* qv = ens ? eq + i*128 : cq + i*128;
    // phase 1: qf[dp] = bv[h*64+dp] + W[h*64+dp][:].qv
    for (int it = 0; it < 16; ++it) {
      int dp = it*4 + wave;
      const float* wrow = W + (h*64 + dp)*128;
      float acc = wrow[lane]*qv[lane] + wrow[lane+64]*qv[lane+64];
#pragma unroll
      for (int off = 32; off > 0; off >>= 1) acc += __shfl_down(acc, off);
      if (lane == 0) qf[dp] = acc + bv[h*64 + dp];
    }
    __syncthreads();
    // phase 2: QK[e] = sum_dp qf[dp]*Wk[dp][e]
    if (tid < 128) {
      int e = tid;
      const float* Wk = W + (128 + h*64)*128 + e;
      float a0=0.f,a1=0.f,a2=0.f,a3=0.f;
      for (int dp = 0; dp < 64; dp += 4) {
        a0 += qf[dp+0] * Wk[(dp+0)*128];
        a1 += qf[dp+1] * Wk[(dp+1)*128];
        a2 += qf[dp+2] * Wk[(dp+2)*128];
        a3 += qf[dp+3] * Wk[(dp+3)*128];
      }
      wsf[(ens ? QK_ENS : QK_GRP) + bi*128 + e] = (a0+a1)+(a2+a3);
    }
    if (wave == 3) {                     // QB = qf . bk
      float acc = qf[lane] * bv[128 + h*64 + lane];
#pragma unroll
      for (int off = 32; off > 0; off >>= 1) acc += __shfl_down(acc, off);
      if (lane == 0) wsf[(ens ? QB_ENS : QB_GRP) + bi] = acc;
    }
  } else if (blk < 1584) {               // Mplain[gi][r][ep]
    int b2 = blk - 48;
    int gi = b2 >> 7, r = b2 & 127;
    int ep = tid, h = ep >> 7, e = ep & 127;
    const float* wo = gow + gi*16384 + r*128 + h*64;
    const float* wv = giw + gi*49152 + (256 + h*64)*128 + e;
    float a0=0.f,a1=0.f,a2=0.f,a3=0.f;
    for (int hd = 0; hd < 64; hd += 4) {
      a0 += wo[hd+0] * wv[(hd+0)*128];
      a1 += wo[hd+1] * wv[(hd+1)*128];
      a2 += wo[hd+2] * wv[(hd+2)*128];
      a3 += wo[hd+3] * wv[(hd+3)*128];
    }
    Mplain[(gi*128 + r)*256 + ep] = (a0+a1)+(a2+a3);
  } else if (blk < 1712) {               // MeB A-frag
    int f2 = (blk - 1584)*256 + tid;
    int r = f2 >> 8, ep = f2 & 255;
    int h = ep >> 7, e = ep & 127;
    const float* wo = eow + r*128 + h*64;
    const float* wv = eiw + (256 + h*64)*128 + e;
    float a0=0.f,a1=0.f,a2=0.f,a3=0.f;
    for (int hd = 0; hd < 64; hd += 4) {
      a0 += wo[hd+0] * wv[(hd+0)*128];
      a1 += wo[hd+1] * wv[(hd+1)*128];
      a2 += wo[hd+2] * wv[(hd+2)*128];
      a3 += wo[hd+3] * wv[(hd+3)*128];
    }
    float acc = (a0+a1)+(a2+a3);
    int mt = r >> 4, lr = r & 15, kt = ep >> 5, q = (ep >> 3) & 3, j = ep & 7;
    MeB[((mt*8 + kt)*64 + (q*16 + lr))*8 + j] = f2bf(acc);
  } else if (blk < 2096) {               // CGRP (1536 wave-tasks)
    int id = (blk - 1712)*4 + wave;
    int i = id >> 7, d = id & 127;
    const float* wrow = gow + i*16384 + d*128;
    const float* bvv = gib + i*384 + 256;
    float acc = wrow[lane]*bvv[lane] + wrow[lane+64]*bvv[lane+64];
#pragma unroll
    for (int off = 32; off > 0; off >>= 1) acc += __shfl_down(acc, off);
    if (lane == 0) wsf[CGRP + id] = acc + gob[i*128 + d];
  } else if (blk < 2128) {               // CENS (128 wave-tasks)
    int d = (blk - 2096)*4 + wave;
    const float* wrow = eow + d*128;
    const float* bvv = eib + 256;
    float acc = wrow[lane]*bvv[lane] + wrow[lane+64]*bvv[lane+64];
#pragma unroll
    for (int off = 32; off > 0; off >>= 1) acc += __shfl_down(acc, off);
    if (lane == 0) wsf[CENS + d] = acc + eob[d];
  } else {                               // F-zero: 19456 uint4
    int idx = (blk - 2128)*256 + tid;
    if (idx < 19456) ((uint4*)Fws)[idx] = (uint4){0,0,0,0};
  }
}

// ---------------------------------------------------------------------------
// P2: F-build (A-frags, 192 blocks) + qkeB (16) + cwq (52). Grid 260 x 256.
// ---------------------------------------------------------------------------
__global__ void hwe_p2(const float* __restrict__ cw, const float* __restrict__ cb,
                       const float* __restrict__ ce, const float* __restrict__ Mplain,
                       const float* __restrict__ wsf,
                       unsigned short* __restrict__ Fws,
                       unsigned short* __restrict__ qkeB, float* __restrict__ cwq) {
  int blk = blockIdx.x, tid = threadIdx.x;
  if (blk < 192) {                      // F_h[r][k] = sum_e M_h[r][e]*cw2[k][e]
    __shared__ __align__(16) unsigned short M16[16*130];
    __shared__ __align__(16) unsigned short cwl[85*130];
    int gi = blk >> 4, h = (blk >> 3) & 1, mt = blk & 7;
    int go = GOFF[gi], K5 = K5A[gi], S = SLOTS3[gi];
    int r0 = mt*16;
    for (int idx = tid; idx < 2048; idx += 256) {
      int rr = idx >> 7, e = idx & 127;
      M16[rr*130 + e] = f2bf(Mplain[(gi*128 + r0 + rr)*256 + h*128 + e]);
    }
    for (int idx = tid; idx < K5*128; idx += 256) {
      int k = idx >> 7, e = idx & 127;
      int q = (k*205) >> 10;
      int pp = k - q*5;
      int s = GSLOT[go + q];
      int v = (s < 45) ? s : s + 20;
      float val = (pp < 4) ? cw[(v*4 + pp)*128 + e] : (cb[v*128 + e] + ce[v*128 + e]);
      cwl[k*130 + e] = f2bf(val);
    }
    __syncthreads();
    const unsigned* M32 = (const unsigned*)M16;
    const unsigned* C32 = (const unsigned*)cwl;
    for (int o = tid; o < 16*K5; o += 256) {
      int k = o >> 4, rr = o & 15;
      float acc = 0.f;
#pragma unroll 8
      for (int e2 = 0; e2 < 64; ++e2) {
        unsigned m = M32[rr*65 + e2];
        unsigned c = C32[k*65 + e2];
        acc += __uint_as_float(m << 16) * __uint_as_float(c << 16);
        acc += __uint_as_float(m & 0xffff0000u) * __uint_as_float(c & 0xffff0000u);
      }
      int kpp = h*K5 + k;
      int ktl = kpp >> 5;
      int addr = (FOFFA[gi]*8 + mt*S + ktl)*512 + ((kpp >> 3) & 3)*128 + rr*8 + (kpp & 7);
      Fws[addr] = f2bf(acc);
    }
  } else if (blk < 208) {               // qkeB B-frag from QK_ENS
    int f4 = (blk - 192)*256 + tid;     // [0,4096)
    int lane = (f4 >> 3) & 63, j = f4 & 7;
    int th = ((f4 >> 11) & 1)*16 + (lane & 15);
    int kt = (f4 >> 9) & 3;
    float val = (th < 24) ? wsf[QK_ENS + th*128 + kt*32 + (lane >> 4)*8 + j] : 0.f;
    qkeB[f4] = f2bf(val);
  } else {                              // cwq: wave per (gg,h)
    int wid = (blk - 208)*4 + (tid >> 6);
    int lane = tid & 63;
    if (wid < 206) {
      int gg = wid >> 1, h = wid & 1;
      int gi = GIDX[gg];
      int s = GSLOT[gg];
      int v = (s < 45) ? s : s + 20;
      const float* qk = wsf + QK_GRP + (gi*2 + h)*128;
      float q0 = qk[lane], q1 = qk[lane + 64];
      float a[5];
#pragma unroll
      for (int pp = 0; pp < 4; ++pp)
        a[pp] = cw[(v*4 + pp)*128 + lane]*q0 + cw[(v*4 + pp)*128 + lane + 64]*q1;
      a[4] = (cb[v*128 + lane] + ce[v*128 + lane])*q0 +
             (cb[v*128 + lane + 64] + ce[v*128 + lane + 64])*q1;
#pragma unroll
      for (int off = 32; off > 0; off >>= 1)
#pragma unroll
        for (int kk = 0; kk < 5; ++kk) a[kk] += __shfl_down(a[kk], off);
      if (lane == 0) {
        float* o = cwq + (gg*2 + h)*8;
        o[0] = a[0]*0.125f; o[1] = a[1]*0.125f; o[2] = a[2]*0.125f; o[3] = a[3]*0.125f;
        o[4] = (a[4] + wsf[QB_GRP + gi*2 + h]) * 0.125f;
      }
    }
  }
}

// ---------------------------------------------------------------------------
// Main kernel. grid 1024, block 256 (4 waves). 8 patches per block.
// LDS (bytes), total 63168:
//   region0 [0,28672):
//     A/B: xpB@0 [8p][68][4]us 4352; scb@4352 [8p][2h][104]us 3328;
//          wpAll@7680 [20slot][64][8]us 20480  (ends 28160)
//     C:   Gl@0 [2lp][128r][40]us 20480 (stride 40 = conflict-free writes);
//          apB@20480 [8p][64][8]us 8192  (ends 28672)
//   outg2@28672 [104][136]us 28288   (rows 96..103 zeroed = s-phantom)
//     outg2 16B chunks are XOR-swizzled: chunk' = chunk ^ ((row>>3)&7).
//     C3 B-frag reads stride 8 rows/lane (2176 B == 0 mod 128 B) -> was a
//     16-way bank conflict; swizzle spreads the 8-row-step lanes 8 ways.
//   sce2@56960 [192][16]us 6144
//   stats@63104 float[16]
// ---------------------------------------------------------------------------
__global__ __launch_bounds__(256, 2) void hwe_main(
    const float* __restrict__ x,
    const float* __restrict__ lgam, const float* __restrict__ lbet,
    const float* __restrict__ wsf,  const float* __restrict__ cwq,
    const unsigned short* __restrict__ Fws, const unsigned short* __restrict__ MeB,
    const unsigned short* __restrict__ qkeB,
    float* __restrict__ out) {
  __shared__ __align__(16) unsigned char smem[63168];
  unsigned short* xpB   = (unsigned short*)(smem);
  unsigned short* scb   = (unsigned short*)(smem + 4352);
  unsigned short* wpAll = (unsigned short*)(smem + 7680);
  unsigned short* Gl    = (unsigned short*)(smem);          // C overlay
  unsigned short* apB   = (unsigned short*)(smem + 20480);  // C overlay
  unsigned short* outg2 = (unsigned short*)(smem + 28672);
  unsigned short* sce2  = (unsigned short*)(smem + 56960);
  float*          stats = (float*)(smem + 63104);

  const int tid  = threadIdx.x;
  const int wave = tid >> 6;
  const int lane = tid & 63;
  const int quad = lane >> 4;
  const int l15  = lane & 15;

  const int hi   = blockIdx.x >> 4;
  const int wib  = (blockIdx.x & 15) << 3;
  const int nbase = hi*128 + wib;

  // ---- A1: pixels + zero phantom outg2 rows 96..103 ----
  for (int idx = tid; idx < 2176; idx += 256) {
    int c = idx & 15, r = (idx >> 4) & 1, s = idx >> 5;
    int v = (s < 45) ? s : s + 20;
    float val = x[(v*128 + 2*hi + r)*256 + 2*wib + c];
    int p = c >> 1, pp = r*2 + (c & 1);
    xpB[(p*68 + s)*4 + pp] = f2bf(val);
  }
  for (int idx = tid; idx < 544; idx += 256)
    ((unsigned*)outg2)[96*68 + idx] = 0;
  __syncthreads();

  // ---- A2: group scores via cwq fold ----
  for (int idx = tid; idx < 1648; idx += 256) {
    int h = idx & 1, p = (idx >> 1) & 7, gg = idx >> 4;
    int s = GSLOT[gg];
    const float* c = cwq + (gg*2 + h)*8;
    const unsigned short* xr = xpB + (p*68 + s)*4;
    float acc = c[4] + bf2f(xr[0])*c[0] + bf2f(xr[1])*c[1]
                     + bf2f(xr[2])*c[2] + bf2f(xr[3])*c[3];
    scb[(p*2 + h)*104 + gg] = f2bf(acc);
  }
  __syncthreads();

  // ---- A3: softmax per (p,h,group) ----
  if (tid < 192) {
    int gi = tid % 12, h = (tid / 12) & 1, p = tid / 24;
    int go = GOFF[gi], G = GOFF[gi+1] - go;
    unsigned short* row = scb + (p*2 + h)*104 + go;
    float m = -1e30f;
    for (int g = 0; g < G; ++g) m = fmaxf(m, bf2f(row[g]));
    float ssum = 0.f;
    for (int g = 0; g < G; ++g) {
      float ev = __expf(bf2f(row[g]) - m);
      ssum += ev;
      row[g] = f2bf(ev);
    }
    float inv = 1.f / ssum;
    for (int g = 0; g < G; ++g) row[g] = f2bf(bf2f(row[g]) * inv);
  }
  __syncthreads();

  // ---- Phase B: two halves of 6 groups; F-folded single GEMM per group ----
  for (int hb = 0; hb < 2; ++hb) {
    const int nsl = hb ? 20 : 18;
    const int sbase = hb ? 18 : 0;

    // Fws prefetch machinery: register double-buffer; all indices are
    // compile-time after full unroll (rule #20: no runtime-indexed arrays).
    short8 fA[6], fB[6];
    auto fws_issue = [&](int I, short8 (&buf)[6]) {
      int pi = I*4 + wave;
      int gi = hb*6 + (pi >> 3), mt = pi & 7;
      int S = SLOTS3[gi];
      const unsigned short* fp = Fws + (FOFFA[gi]*8 + mt*S)*512 + lane*8;
#pragma unroll
      for (int kt = 0; kt < 6; ++kt)
        if (kt < S) buf[kt] = *(const short8*)(fp + kt*512);
    };
    auto fws_compute = [&](int I, short8 (&buf)[6]) {
      int pi = I*4 + wave;
      int gi = hb*6 + (pi >> 3), mt = pi & 7;
      int S = SLOTS3[gi];
      int lbase = FOFFA[gi] - sbase;
      f32x4 acc = {0.f,0.f,0.f,0.f};
#pragma unroll
      for (int kt = 0; kt < 6; ++kt)
        if (kt < S) {
          short8 b = *(const short8*)(wpAll + (lbase + kt)*512 + lane*8);
          acc = __builtin_amdgcn_mfma_f32_16x16x32_bf16(buf[kt], b, acc, 0, 0, 0);
        }
      if (l15 < 8) {
        int p = l15;
        int rb = mt*16 + quad*4;
        float4 cg = *(const float4*)(wsf + CGRP + gi*128 + rb);
        unsigned short t0 = f2bf(acc[0] + cg.x);
        unsigned short t1 = f2bf(acc[1] + cg.y);
        unsigned short t2 = f2bf(acc[2] + cg.z);
        unsigned short t3 = f2bf(acc[3] + cg.w);
        uint2 w;
        w.x = (unsigned)t0 | ((unsigned)t1 << 16);
        w.y = (unsigned)t2 | ((unsigned)t3 << 16);
        int row = gi*8 + p;                    // row>>3 == gi
        int ch = (rb >> 3) ^ (gi & 7);         // swizzled 16B chunk
        *(uint2*)(outg2 + row*136 + ch*8 + (rb & 7)) = w;
      }
    };

    // issue task 0's Fws loads now: they complete under zero+fill+barrier
    fws_issue(0, fA);

    for (int i = tid; i < nsl*64; i += 256)
      *(uint4*)(wpAll + i*8) = (uint4){0,0,0,0};
    __syncthreads();
    {
      const int total = hb ? 4720 : 3520;
      for (int idx = tid; idx < total; idx += 256) {
        int gil = 0;
#pragma unroll
        for (int t6 = 1; t6 < 6; ++t6) {
          int eo = hb ? EOFF1[t6] : EOFF0[t6];
          if (idx >= eo) gil = t6;
        }
        int gi = hb*6 + gil;
        int local = idx - (hb ? EOFF1[gil] : EOFF0[gil]);
        int kpp = local >> 3, p = local & 7;
        int K5 = K5A[gi];
        int h = (kpp >= K5) ? 1 : 0;
        int k = kpp - (h ? K5 : 0);
        int q = (k*205) >> 10;
        int pp = k - q*5;
        int gg = GOFF[gi] + q;
        float a = bf2f(scb[(p*2 + h)*104 + gg]);
        float val = (pp < 4) ? a * bf2f(xpB[(p*68 + GSLOT[gg])*4 + pp]) : a;
        int ls = (FOFFA[gi] - sbase) + (kpp >> 5);
        wpAll[ls*512 + ((kpp >> 3) & 3)*128 + p*8 + (kpp & 7)] = f2bf(val);
      }
    }
    __syncthreads();

    // software-pipelined task loop: issue(i+1) before compute(i)
#pragma unroll
    for (int ii = 0; ii < 6; ++ii) {
      fws_issue(ii*2 + 1, fB);
      fws_compute(ii*2, fA);
      if (ii < 5) fws_issue(ii*2 + 2, fA);
      fws_compute(ii*2 + 1, fB);
    }
    __syncthreads();
  }

  // ---- C1: ens scores GEMM (M=96 rows (s,p), N=24 (t,h), K=128) ----
#pragma unroll
  for (int ti = 0; ti < 3; ++ti) {
    int T = wave*3 + ti;
    int mtp = T >> 1, ntp = T & 1;
    int rowA = mtp*16 + l15;
    int sx = (rowA >> 3) & 7;
    f32x4 acc = {0.f,0.f,0.f,0.f};
#pragma unroll
    for (int kt = 0; kt < 4; ++kt) {
      short8 a = *(const short8*)(outg2 + rowA*136 + ((kt*4 + quad) ^ sx)*8);
      short8 b = *(const short8*)(qkeB + ((ntp*4 + kt)*64 + lane)*8);
      acc = __builtin_amdgcn_mfma_f32_16x16x32_bf16(a, b, acc, 0, 0, 0);
    }
    int th = ntp*16 + l15;
    if (th < 24) {
      float qb = wsf[QB_ENS + th];
#pragma unroll
      for (int reg = 0; reg < 4; ++reg) {
        int rowE = mtp*16 + quad*4 + reg;
        sce2[((rowE & 7)*24 + th)*16 + (rowE >> 3)] = f2bf((acc[reg] + qb) * 0.125f);
      }
    }
  }
  __syncthreads();

  // ---- C2: softmax over s per (p, t, h) ----
  if (tid < 192) {
    unsigned short* row = sce2 + tid*16;
    float m = -1e30f;
    for (int s = 0; s < 12; ++s) m = fmaxf(m, bf2f(row[s]));
    float ssum = 0.f;
    for (int s = 0; s < 12; ++s) {
      float ev = __expf(bf2f(row[s]) - m);
      ssum += ev;
      row[s] = f2bf(ev);
    }
    float inv = 1.f / ssum;
    for (int s = 0; s < 12; ++s) row[s] = f2bf(bf2f(row[s]) * inv);
  }
  __syncthreads();

  // ---- apB: attn weights as B-frags ----
  for (int idx = tid; idx < 4096; idx += 256) {
    int p = idx >> 9, r9 = idx & 511;
    int ln = r9 >> 3, j = r9 & 7;
    int t = ln & 15, qd = ln >> 4;
    int kpp = qd*8 + j;
    int h = kpp >> 4, s = kpp & 15;
    unsigned short v = 0;
    if (s < 12 && t < 12) v = sce2[(p*24 + t*2 + h)*16 + s];
    apB[p*512 + ln*8 + j] = v;
  }
  // preload cens + MeB fragments (reused across all 4 C3 periods)
  float cens0[4], cens1[4];
  {
    float4 c0 = *(const float4*)(wsf + CENS + (wave*2 + 0)*16 + quad*4);
    float4 c1 = *(const float4*)(wsf + CENS + (wave*2 + 1)*16 + quad*4);
    cens0[0]=c0.x; cens0[1]=c0.y; cens0[2]=c0.z; cens0[3]=c0.w;
    cens1[0]=c1.x; cens1[1]=c1.y; cens1[2]=c1.z; cens1[3]=c1.w;
  }
  short8 meAr[16];   // [mi][h][kt]
#pragma unroll
  for (int mi = 0; mi < 2; ++mi)
#pragma unroll
    for (int h = 0; h < 2; ++h)
#pragma unroll
      for (int kt = 0; kt < 4; ++kt)
        meAr[(mi*2 + h)*4 + kt] =
          *(const short8*)(MeB + (((wave*2 + mi)*8 + h*4 + kt)*64 + lane)*8);
  __syncthreads();

  // ---- C3: 2 patches per period: G-GEMM -> R-GEMM -> register LayerNorm ----
  for (int pp2 = 0; pp2 < 4; ++pp2) {
    f32x4 g[2][2][2];  // [lp][mi][h]
#pragma unroll
    for (int lp = 0; lp < 2; ++lp)
#pragma unroll
      for (int mi = 0; mi < 2; ++mi)
#pragma unroll
        for (int h = 0; h < 2; ++h) g[lp][mi][h] = (f32x4){0.f,0.f,0.f,0.f};
#pragma unroll
    for (int lp = 0; lp < 2; ++lp) {
      int p = pp2*2 + lp;
      int brow = (l15 < 12 ? l15 : 12)*8 + p;   // phantom s -> zero row 96+p
      int sx = (brow >> 3) & 7;
#pragma unroll
      for (int h = 0; h < 2; ++h) {
#pragma unroll
        for (int kt = 0; kt < 4; ++kt) {
          short8 b = *(const short8*)(outg2 + brow*136 + ((kt*4 + quad) ^ sx)*8);
          g[lp][0][h] = __builtin_amdgcn_mfma_f32_16x16x32_bf16(
              meAr[(0*2 + h)*4 + kt], b, g[lp][0][h], 0, 0, 0);
          g[lp][1][h] = __builtin_amdgcn_mfma_f32_16x16x32_bf16(
              meAr[(1*2 + h)*4 + kt], b, g[lp][1][h], 0, 0, 0);
        }
      }
    }
    // write G to LDS: Gl[lp][r][h*16+s], row stride 40 (conflict-free)
#pragma unroll
    for (int lp = 0; lp < 2; ++lp)
#pragma unroll
      for (int mi = 0; mi < 2; ++mi)
#pragma unroll
        for (int h = 0; h < 2; ++h)
#pragma unroll
          for (int reg = 0; reg < 4; ++reg) {
            int r = (wave*2 + mi)*16 + quad*4 + reg;
            Gl[lp*5120 + r*40 + h*16 + l15] = f2bf(g[lp][mi][h][reg]);
          }
    __syncthreads();

    // R-GEMM: R[r][t] = G @ a'  (K=32)
    f32x4 rr[2][2];
    float s1[2] = {0.f, 0.f}, s2[2] = {0.f, 0.f};
#pragma unroll
    for (int lp = 0; lp < 2; ++lp) {
      int p = pp2*2 + lp;
      short8 bfrag = *(const short8*)(apB + p*512 + lane*8);
#pragma unroll
      for (int mi = 0; mi < 2; ++mi) {
        int mt2 = wave*2 + mi;
        short8 afrag = *(const short8*)(Gl + lp*5120 + (mt2*16 + l15)*40 + quad*8);
        f32x4 acc = {0.f,0.f,0.f,0.f};
        acc = __builtin_amdgcn_mfma_f32_16x16x32_bf16(afrag, bfrag, acc, 0, 0, 0);
#pragma unroll
        for (int reg = 0; reg < 4; ++reg)
          acc[reg] += (mi ? cens1[reg] : cens0[reg]);
        rr[lp][mi] = acc;
        if (l15 < 12) {
#pragma unroll
          for (int reg = 0; reg < 4; ++reg) {
            float v = acc[reg];
            s1[lp] += v; s2[lp] += v*v;
          }
        }
      }
    }
#pragma unroll
    for (int off = 32; off > 0; off >>= 1) {
#pragma unroll
      for (int lp = 0; lp < 2; ++lp) {
        s1[lp] += __shfl_xor(s1[lp], off);
        s2[lp] += __shfl_xor(s2[lp], off);
      }
    }
    if (lane == 0) {
#pragma unroll
      for (int lp = 0; lp < 2; ++lp) {
        stats[lp*4 + wave] = s1[lp];
        stats[8 + lp*4 + wave] = s2[lp];
      }
    }
    __syncthreads();
#pragma unroll
    for (int lp = 0; lp < 2; ++lp) {
      float t1 = stats[lp*4+0] + stats[lp*4+1] + stats[lp*4+2] + stats[lp*4+3];
      float t2 = stats[8+lp*4+0] + stats[8+lp*4+1] + stats[8+lp*4+2] + stats[8+lp*4+3];
      float mean = t1 * (1.f/1536.f);
      float var  = t2 * (1.f/1536.f) - mean*mean;
      float rstd = rsqrtf(var + 1e-5f);
      if (l15 < 12) {
        long nrow = (long)(nbase + pp2*2 + lp) * 1536;
#pragma unroll
        for (int mi = 0; mi < 2; ++mi) {
          int rb = (wave*2 + mi)*16 + quad*4;
          int j = l15*128 + rb;
          float4 gm = *(const float4*)(lgam + j);
          float4 bt = *(const float4*)(lbet + j);
          float4 o;
          o.x = (rr[lp][mi][0] - mean)*rstd*gm.x + bt.x;
          o.y = (rr[lp][mi][1] - mean)*rstd*gm.y + bt.y;
          o.z = (rr[lp][mi][2] - mean)*rstd*gm.z + bt.z;
          o.w = (rr[lp][mi][3] - mean)*rstd*gm.w + bt.w;
          *(float4*)(out + nrow + j) = o;
        }
      }
    }
    __syncthreads();
  }
}

// ---------------------------------------------------------------------------
extern "C" void kernel_launch(void* const* d_in, const int* in_sizes, int n_in,
                              void* d_out, int out_size, void* d_ws, size_t ws_size,
                              hipStream_t stream) {
  const float* x   = (const float*)d_in[0];
  const float* cw  = (const float*)d_in[1];
  const float* cb  = (const float*)d_in[2];
  const float* ce  = (const float*)d_in[3];
  const float* cq  = (const float*)d_in[4];
  const float* giw = (const float*)d_in[5];
  const float* gib = (const float*)d_in[6];
  const float* gow = (const float*)d_in[7];
  const float* gob = (const float*)d_in[8];
  const float* eq  = (const float*)d_in[9];
  const float* eiw = (const float*)d_in[10];
  const float* eib = (const float*)d_in[11];
  const float* eow = (const float*)d_in[12];
  const float* eob = (const float*)d_in[13];
  const float* lg  = (const float*)d_in[14];
  const float* lb  = (const float*)d_in[15];

  float* wsf = (float*)d_ws;
  float* cwq = (float*)((char*)d_ws + CWQ_BYTE);
  float* Mplain = (float*)((char*)d_ws + MPL_BYTE);
  unsigned short* MeB  = (unsigned short*)((char*)d_ws + MEB_BYTE);
  unsigned short* qkeB = (unsigned short*)((char*)d_ws + QKEB_BYTE);
  unsigned short* Fws  = (unsigned short*)((char*)d_ws + FWS_BYTE);

  hwe_p1<<<2204, 256, 0, stream>>>(giw, gib, gow, gob, cq, eq, eiw, eib, eow, eob,
                                   wsf, Mplain, MeB, Fws);
  hwe_p2<<<260, 256, 0, stream>>>(cw, cb, ce, Mplain, wsf, Fws, qkeB, cwq);
  hwe_main<<<1024, 256, 0, stream>>>(x, lg, lb, wsf, cwq, Fws, MeB, qkeB,
                                     (float*)d_out);
}

// Round 2
// 205.135 us; speedup vs baseline: 1.3354x; 1.3354x over previous
//
#include <hip/hip_runtime.h>

// ---------------------------------------------------------------------------
// HieraWeatherEmbedding R9: occupancy push (2 -> 3 blocks/CU).
//  - LDS 63168 -> 53632 B: outg2 stride 136->128 us with dual-key swizzle
//    key=((row>>3)^row)&7 (read- AND write-side conflict-free at pow2 stride);
//    single shared phantom zero row (96); sce2 overlays dead xpB/scb region.
//  - Barrier diet: fused position-major wpAll fill (no pre-zero pass);
//    C3 Gl transpose is intra-wave -> no barrier; stats double-buffered ->
//    no period-end barrier.  ~22 -> 14 barriers.
//  - constexpr slot tables: Fws task loop constant-folds (no guards);
//    CGRP float4 rides the register prefetch pipeline.
//  - float2-vectorized x loads; register-resident softmax (A3/C2).
// fp32 I/O, bf16 fragments, fp32 accumulate.
// ---------------------------------------------------------------------------

typedef __attribute__((ext_vector_type(8))) short short8;
typedef __attribute__((ext_vector_type(4))) float f32x4;

__constant__ int GOFF[13] = {0,7,14,21,28,35,44,53,62,71,80,97,103};
__constant__ int K5A[12]  = {35,35,35,35,35,45,45,45,45,45,85,30};
__constant__ int SLOTS3[12] = {3,3,3,3,3,3,3,3,3,3,6,2};
__constant__ int FOFFA[12] = {0,3,6,9,12,15,18,21,24,27,30,36};   // slot offsets (total 38)
__constant__ int GSLOT[103] = {
  3,8,13,18,23,28,33,
  4,9,14,19,24,29,34,
  2,7,12,17,22,27,32,
  1,6,11,16,21,26,31,
  0,5,10,15,20,25,30,
  3,8,13,18,23,28,33,38,43,
  4,9,14,19,24,29,34,39,44,
  2,7,12,17,22,27,32,37,42,
  1,6,11,16,21,26,31,36,41,
  0,5,10,15,20,25,30,35,40,
  45,46,47,48,49,50,51,52,53,54,55,56,57,58,59,60,61,
  62,63,64,65,66,67};
__constant__ int GIDX[103] = {
  0,0,0,0,0,0,0, 1,1,1,1,1,1,1, 2,2,2,2,2,2,2, 3,3,3,3,3,3,3, 4,4,4,4,4,4,4,
  5,5,5,5,5,5,5,5,5, 6,6,6,6,6,6,6,6,6, 7,7,7,7,7,7,7,7,7, 8,8,8,8,8,8,8,8,8,
  9,9,9,9,9,9,9,9,9,
  10,10,10,10,10,10,10,10,10,10,10,10,10,10,10,10,10,
  11,11,11,11,11,11};

// compile-time copies for the main kernel's fully-unrolled task loop
constexpr int cSLOTS[12] = {3,3,3,3,3,3,3,3,3,3,6,2};
constexpr int cFOFFA[12] = {0,3,6,9,12,15,18,21,24,27,30,36};

// fp32 workspace region (float offsets)
#define QK_GRP 0        // [12][2][128]
#define QK_ENS 3072     // [24][128]
#define QB_GRP 6144     // [12][2]
#define QB_ENS 6176     // [24]
#define CGRP   6208     // [12][128]
#define CENS   7744     // [128]
// byte offsets
#define CWQ_BYTE   43776    // float [103][2][8]
#define MPL_BYTE   50432    // float [12][128][256]   (1572864 B)
#define MEB_BYTE   1623296  // ushort [8mt][8kt][64][8] (65536 B)
#define QKEB_BYTE  1688832  // ushort [2nt][4kt][64][8] (8192 B)
#define FWS_BYTE   1697024  // ushort 304 frags * 512  (311296 B)

__device__ __forceinline__ float bf2f(unsigned short s) {
  return __uint_as_float(((unsigned)s) << 16);
}
__device__ __forceinline__ unsigned short f2bf(float f) {
  unsigned u = __float_as_uint(f);
  u += 0x7fffu + ((u >> 16) & 1u);
  return (unsigned short)(u >> 16);
}

// ---------------------------------------------------------------------------
// P1: QK/QB direct (two-phase in-block), CGRP, CENS, Mplain, MeB, F-zero.
// Grid 2204 x 256.
// ---------------------------------------------------------------------------
__global__ void hwe_p1(const float* __restrict__ giw, const float* __restrict__ gib,
                       const float* __restrict__ gow, const float* __restrict__ gob,
                       const float* __restrict__ cq,  const float* __restrict__ eq,
                       const float* __restrict__ eiw, const float* __restrict__ eib,
                       const float* __restrict__ eow, const float* __restrict__ eob,
                       float* __restrict__ wsf, float* __restrict__ Mplain,
                       unsigned short* __restrict__ MeB, unsigned short* __restrict__ Fws) {
  int blk = blockIdx.x, tid = threadIdx.x;
  int wave = tid >> 6, lane = tid & 63;
  if (blk < 48) {                        // QK + QB for (i,h) grp / (t,h) ens
    __shared__ float qf[64];
    bool ens = blk >= 24;
    int bi = ens ? blk - 24 : blk;
    int i = bi >> 1, h = bi & 1;
    const float* W  = ens ? eiw : giw + i*49152;   // [384][128]
    const float* bv = ens ? eib : gib + i*384;     // [384]
    const float* qv = ens ? eq + i*128 : cq + i*128;
    // phase 1: qf[dp] = bv[h*64+dp] + W[h*64+dp][:].qv
    for (int it = 0; it < 16; ++it) {
      int dp = it*4 + wave;
      const float* wrow = W + (h*64 + dp)*128;
      float acc = wrow[lane]*qv[lane] + wrow[lane+64]*qv[lane+64];
#pragma unroll
      for (int off = 32; off > 0; off >>= 1) acc += __shfl_down(acc, off);
      if (lane == 0) qf[dp] = acc + bv[h*64 + dp];
    }
    __syncthreads();
    // phase 2: QK[e] = sum_dp qf[dp]*Wk[dp][e]
    if (tid < 128) {
      int e = tid;
      const float* Wk = W + (128 + h*64)*128 + e;
      float a0=0.f,a1=0.f,a2=0.f,a3=0.f;
      for (int dp = 0; dp < 64; dp += 4) {
        a0 += qf[dp+0] * Wk[(dp+0)*128];
        a1 += qf[dp+1] * Wk[(dp+1)*128];
        a2 += qf[dp+2] * Wk[(dp+2)*128];
        a3 += qf[dp+3] * Wk[(dp+3)*128];
      }
      wsf[(ens ? QK_ENS : QK_GRP) + bi*128 + e] = (a0+a1)+(a2+a3);
    }
    if (wave == 3) {                     // QB = qf . bk
      float acc = qf[lane] * bv[128 + h*64 + lane];
#pragma unroll
      for (int off = 32; off > 0; off >>= 1) acc += __shfl_down(acc, off);
      if (lane == 0) wsf[(ens ? QB_ENS : QB_GRP) + bi] = acc;
    }
  } else if (blk < 1584) {               // Mplain[gi][r][ep]
    int b2 = blk - 48;
    int gi = b2 >> 7, r = b2 & 127;
    int ep = tid, h = ep >> 7, e = ep & 127;
    const float* wo = gow + gi*16384 + r*128 + h*64;
    const float* wv = giw + gi*49152 + (256 + h*64)*128 + e;
    float a0=0.f,a1=0.f,a2=0.f,a3=0.f;
    for (int hd = 0; hd < 64; hd += 4) {
      a0 += wo[hd+0] * wv[(hd+0)*128];
      a1 += wo[hd+1] * wv[(hd+1)*128];
      a2 += wo[hd+2] * wv[(hd+2)*128];
      a3 += wo[hd+3] * wv[(hd+3)*128];
    }
    Mplain[(gi*128 + r)*256 + ep] = (a0+a1)+(a2+a3);
  } else if (blk < 1712) {               // MeB A-frag
    int f2 = (blk - 1584)*256 + tid;
    int r = f2 >> 8, ep = f2 & 255;
    int h = ep >> 7, e = ep & 127;
    const float* wo = eow + r*128 + h*64;
    const float* wv = eiw + (256 + h*64)*128 + e;
    float a0=0.f,a1=0.f,a2=0.f,a3=0.f;
    for (int hd = 0; hd < 64; hd += 4) {
      a0 += wo[hd+0] * wv[(hd+0)*128];
      a1 += wo[hd+1] * wv[(hd+1)*128];
      a2 += wo[hd+2] * wv[(hd+2)*128];
      a3 += wo[hd+3] * wv[(hd+3)*128];
    }
    float acc = (a0+a1)+(a2+a3);
    int mt = r >> 4, lr = r & 15, kt = ep >> 5, q = (ep >> 3) & 3, j = ep & 7;
    MeB[((mt*8 + kt)*64 + (q*16 + lr))*8 + j] = f2bf(acc);
  } else if (blk < 2096) {               // CGRP (1536 wave-tasks)
    int id = (blk - 1712)*4 + wave;
    int i = id >> 7, d = id & 127;
    const float* wrow = gow + i*16384 + d*128;
    const float* bvv = gib + i*384 + 256;
    float acc = wrow[lane]*bvv[lane] + wrow[lane+64]*bvv[lane+64];
#pragma unroll
    for (int off = 32; off > 0; off >>= 1) acc += __shfl_down(acc, off);
    if (lane == 0) wsf[CGRP + id] = acc + gob[i*128 + d];
  } else if (blk < 2128) {               // CENS (128 wave-tasks)
    int d = (blk - 2096)*4 + wave;
    const float* wrow = eow + d*128;
    const float* bvv = eib + 256;
    float acc = wrow[lane]*bvv[lane] + wrow[lane+64]*bvv[lane+64];
#pragma unroll
    for (int off = 32; off > 0; off >>= 1) acc += __shfl_down(acc, off);
    if (lane == 0) wsf[CENS + d] = acc + eob[d];
  } else {                               // F-zero: 19456 uint4
    int idx = (blk - 2128)*256 + tid;
    if (idx < 19456) ((uint4*)Fws)[idx] = (uint4){0,0,0,0};
  }
}

// ---------------------------------------------------------------------------
// P2: F-build (A-frags, 192 blocks) + qkeB (16) + cwq (52). Grid 260 x 256.
// ---------------------------------------------------------------------------
__global__ void hwe_p2(const float* __restrict__ cw, const float* __restrict__ cb,
                       const float* __restrict__ ce, const float* __restrict__ Mplain,
                       const float* __restrict__ wsf,
                       unsigned short* __restrict__ Fws,
                       unsigned short* __restrict__ qkeB, float* __restrict__ cwq) {
  int blk = blockIdx.x, tid = threadIdx.x;
  if (blk < 192) {                      // F_h[r][k] = sum_e M_h[r][e]*cw2[k][e]
    __shared__ __align__(16) unsigned short M16[16*130];
    __shared__ __align__(16) unsigned short cwl[85*130];
    int gi = blk >> 4, h = (blk >> 3) & 1, mt = blk & 7;
    int go = GOFF[gi], K5 = K5A[gi], S = SLOTS3[gi];
    int r0 = mt*16;
    for (int idx = tid; idx < 2048; idx += 256) {
      int rr = idx >> 7, e = idx & 127;
      M16[rr*130 + e] = f2bf(Mplain[(gi*128 + r0 + rr)*256 + h*128 + e]);
    }
    for (int idx = tid; idx < K5*128; idx += 256) {
      int k = idx >> 7, e = idx & 127;
      int q = (k*205) >> 10;
      int pp = k - q*5;
      int s = GSLOT[go + q];
      int v = (s < 45) ? s : s + 20;
      float val = (pp < 4) ? cw[(v*4 + pp)*128 + e] : (cb[v*128 + e] + ce[v*128 + e]);
      cwl[k*130 + e] = f2bf(val);
    }
    __syncthreads();
    const unsigned* M32 = (const unsigned*)M16;
    const unsigned* C32 = (const unsigned*)cwl;
    for (int o = tid; o < 16*K5; o += 256) {
      int k = o >> 4, rr = o & 15;
      float acc = 0.f;
#pragma unroll 8
      for (int e2 = 0; e2 < 64; ++e2) {
        unsigned m = M32[rr*65 + e2];
        unsigned c = C32[k*65 + e2];
        acc += __uint_as_float(m << 16) * __uint_as_float(c << 16);
        acc += __uint_as_float(m & 0xffff0000u) * __uint_as_float(c & 0xffff0000u);
      }
      int kpp = h*K5 + k;
      int ktl = kpp >> 5;
      int addr = (FOFFA[gi]*8 + mt*S + ktl)*512 + ((kpp >> 3) & 3)*128 + rr*8 + (kpp & 7);
      Fws[addr] = f2bf(acc);
    }
  } else if (blk < 208) {               // qkeB B-frag from QK_ENS
    int f4 = (blk - 192)*256 + tid;     // [0,4096)
    int lane = (f4 >> 3) & 63, j = f4 & 7;
    int th = ((f4 >> 11) & 1)*16 + (lane & 15);
    int kt = (f4 >> 9) & 3;
    float val = (th < 24) ? wsf[QK_ENS + th*128 + kt*32 + (lane >> 4)*8 + j] : 0.f;
    qkeB[f4] = f2bf(val);
  } else {                              // cwq: wave per (gg,h)
    int wid = (blk - 208)*4 + (tid >> 6);
    int lane = tid & 63;
    if (wid < 206) {
      int gg = wid >> 1, h = wid & 1;
      int gi = GIDX[gg];
      int s = GSLOT[gg];
      int v = (s < 45) ? s : s + 20;
      const float* qk = wsf + QK_GRP + (gi*2 + h)*128;
      float q0 = qk[lane], q1 = qk[lane + 64];
      float a[5];
#pragma unroll
      for (int pp = 0; pp < 4; ++pp)
        a[pp] = cw[(v*4 + pp)*128 + lane]*q0 + cw[(v*4 + pp)*128 + lane + 64]*q1;
      a[4] = (cb[v*128 + lane] + ce[v*128 + lane])*q0 +
             (cb[v*128 + lane + 64] + ce[v*128 + lane + 64])*q1;
#pragma unroll
      for (int off = 32; off > 0; off >>= 1)
#pragma unroll
        for (int kk = 0; kk < 5; ++kk) a[kk] += __shfl_down(a[kk], off);
      if (lane == 0) {
        float* o = cwq + (gg*2 + h)*8;
        o[0] = a[0]*0.125f; o[1] = a[1]*0.125f; o[2] = a[2]*0.125f; o[3] = a[3]*0.125f;
        o[4] = (a[4] + wsf[QB_GRP + gi*2 + h]) * 0.125f;
      }
    }
  }
}

// ---------------------------------------------------------------------------
// Main kernel. grid 1024, block 256 (4 waves). 8 patches per block.
// LDS (bytes), total 53632 -> 3 blocks/CU:
//   region0 [0,28672):
//     A/B: xpB@0 [8p][68][4]us 4352; scb@4352 [8p][2h][104]us 3328;
//          wpAll@7680 [20slot][64][8]us 20480  (ends 28160)
//     C:   Gl@0 [2lp][128r][40]us 20480 (80 B rows: 16B-aligned b128 reads);
//          apB@20480 [8p][64][8]us 8192  (ends 28672)
//     C':  sce2@0 [192][16]us 6144 (live C1 -> apB fill only; before Gl)
//   outg2@28672 [97][128]us 24832  (row 96 = shared phantom zero row)
//     16B chunks dual-key swizzled: chunk' = chunk ^ (((row>>3)^row)&7)
//     -> conflict-free on BOTH the 8-row-stride C3 reads (key varies with
//        row>>3) and the consecutive-row phase-B writes (key varies with p).
//   stats@53504 float[2][16] (double-buffered -> no period-end barrier)
// ---------------------------------------------------------------------------
__global__ __launch_bounds__(256, 3) void hwe_main(
    const float* __restrict__ x,
    const float* __restrict__ lgam, const float* __restrict__ lbet,
    const float* __restrict__ wsf,  const float* __restrict__ cwq,
    const unsigned short* __restrict__ Fws, const unsigned short* __restrict__ MeB,
    const unsigned short* __restrict__ qkeB,
    float* __restrict__ out) {
  __shared__ __align__(16) unsigned char smem[53632];
  unsigned short* xpB   = (unsigned short*)(smem);
  unsigned short* scb   = (unsigned short*)(smem + 4352);
  unsigned short* wpAll = (unsigned short*)(smem + 7680);
  unsigned short* Gl    = (unsigned short*)(smem);          // C overlay (C3)
  unsigned short* apB   = (unsigned short*)(smem + 20480);  // C overlay
  unsigned short* sce2  = (unsigned short*)(smem);          // C overlay (C1..apB)
  unsigned short* outg2 = (unsigned short*)(smem + 28672);
  float*          stats = (float*)(smem + 53504);           // [2][16]

  const int tid  = threadIdx.x;
  const int wave = tid >> 6;
  const int lane = tid & 63;
  const int quad = lane >> 4;
  const int l15  = lane & 15;

  const int hi   = blockIdx.x >> 4;
  const int wib  = (blockIdx.x & 15) << 3;
  const int nbase = hi*128 + wib;

  // ---- A1: pixels (float2-vectorized) + zero shared phantom row 96 ----
  for (int idx = tid; idx < 1088; idx += 256) {
    int c2 = idx & 7, r = (idx >> 3) & 1, s = idx >> 4;
    int v = (s < 45) ? s : s + 20;
    const float2 xv = *(const float2*)(x + (v*128 + 2*hi + r)*256 + 2*wib + c2*2);
    unsigned pk = (unsigned)f2bf(xv.x) | ((unsigned)f2bf(xv.y) << 16);
    *(unsigned*)(xpB + (c2*68 + s)*4 + r*2) = pk;
  }
  if (tid < 64) ((unsigned*)outg2)[96*64 + tid] = 0u;
  __syncthreads();

  // ---- A2: group scores via cwq fold ----
  for (int idx = tid; idx < 1648; idx += 256) {
    int h = idx & 1, p = (idx >> 1) & 7, gg = idx >> 4;
    int s = GSLOT[gg];
    const float* c = cwq + (gg*2 + h)*8;
    const unsigned short* xr = xpB + (p*68 + s)*4;
    float acc = c[4] + bf2f(xr[0])*c[0] + bf2f(xr[1])*c[1]
                     + bf2f(xr[2])*c[2] + bf2f(xr[3])*c[3];
    scb[(p*2 + h)*104 + gg] = f2bf(acc);
  }
  __syncthreads();

  // ---- A3: softmax per (p,h,group) — register-resident, batched LDS ----
  if (tid < 192) {
    int gi = tid % 12, h = (tid / 12) & 1, p = tid / 24;
    int go = GOFF[gi], G = GOFF[gi+1] - go;
    unsigned short* row = scb + (p*2 + h)*104 + go;
    float ev[17];
    float m = -1e30f;
#pragma unroll
    for (int g = 0; g < 17; ++g) {
      ev[g] = (g < G) ? bf2f(row[g]) : -1e30f;
      m = fmaxf(m, ev[g]);
    }
    float ssum = 0.f;
#pragma unroll
    for (int g = 0; g < 17; ++g) {
      float e = __expf(ev[g] - m);
      ev[g] = e;
      if (g < G) ssum += e;
    }
    float inv = 1.f / ssum;
#pragma unroll
    for (int g = 0; g < 17; ++g)
      if (g < G) row[g] = f2bf(ev[g] * inv);
  }
  __syncthreads();

  // ---- Phase B: two halves of 6 groups; F-folded single GEMM per group ----
#pragma unroll
  for (int hb = 0; hb < 2; ++hb) {
    const int nsl = hb ? 20 : 18;
    const int sbase = hb ? 18 : 0;

    short8 fA[6], fB[6];
    float4 cgA, cgB;
    auto fws_issue = [&](int I, short8 (&buf)[6], float4& cg) {
      int gi = hb*6 + (I >> 1);          // compile-time after unroll
      int S  = cSLOTS[gi];
      int mt = (I & 1)*4 + wave;
      const unsigned short* fp = Fws + (cFOFFA[gi]*8 + mt*S)*512 + lane*8;
#pragma unroll
      for (int kt = 0; kt < 6; ++kt)
        if (kt < S) buf[kt] = *(const short8*)(fp + kt*512);
      cg = *(const float4*)(wsf + CGRP + gi*128 + mt*16 + quad*4);
    };
    auto fws_compute = [&](int I, short8 (&buf)[6], const float4& cg) {
      int gi = hb*6 + (I >> 1);
      int S  = cSLOTS[gi];
      int mt = (I & 1)*4 + wave;
      int lbase = cFOFFA[gi] - sbase;
      f32x4 acc = {0.f,0.f,0.f,0.f};
#pragma unroll
      for (int kt = 0; kt < 6; ++kt)
        if (kt < S) {
          short8 b = *(const short8*)(wpAll + (lbase + kt)*512 + lane*8);
          acc = __builtin_amdgcn_mfma_f32_16x16x32_bf16(buf[kt], b, acc, 0, 0, 0);
        }
      if (l15 < 8) {
        int p = l15;
        int rb = mt*16 + quad*4;
        unsigned short t0 = f2bf(acc[0] + cg.x);
        unsigned short t1 = f2bf(acc[1] + cg.y);
        unsigned short t2 = f2bf(acc[2] + cg.z);
        unsigned short t3 = f2bf(acc[3] + cg.w);
        uint2 w;
        w.x = (unsigned)t0 | ((unsigned)t1 << 16);
        w.y = (unsigned)t2 | ((unsigned)t3 << 16);
        int row = gi*8 + p;
        int ch = (rb >> 3) ^ ((gi ^ p) & 7);      // dual-key swizzle
        *(uint2*)(outg2 + row*128 + ch*8 + (rb & 7)) = w;
      }
    };

    // issue task 0's Fws/CGRP loads: complete under fill + barrier
    fws_issue(0, fA, cgA);

    // ---- fused position-major fill: every wpAll ushort written once ----
    {
      const int nposs = nsl * 512;
      for (int pos = tid*4; pos < nposs; pos += 1024) {
        int pf = (pos >> 3) & 15;
        uint2 w2 = {0u, 0u};
        if (pf < 8) {
          int ls = pos >> 9;
          int qd = (pos >> 7) & 3;
          int j0 = pos & 7;                    // 0 or 4
          int p  = pf;
          int gil, K5, fo, goffB, c0, stp;
          if (hb == 0) {
            gil = (ls>=3)+(ls>=6)+(ls>=9)+(ls>=12)+(ls>=15);
            K5 = (gil < 5) ? 35 : 45;
            fo = gil*3;
            goffB = gil*7;
            c0 = (gil==0)?3:(gil==1)?4:(gil==2)?2:(gil==3)?1:(gil==4)?0:3;
            stp = 5;
          } else {
            gil = (ls>=3)+(ls>=6)+(ls>=9)+(ls>=12)+(ls>=18);
            K5 = (gil < 4) ? 45 : (gil == 4) ? 85 : 30;
            fo = (gil < 5) ? gil*3 : 18;
            goffB = (gil < 5) ? (44 + gil*9) : 97;
            c0 = (gil==0)?4:(gil==1)?2:(gil==2)?1:(gil==3)?0:(gil==4)?45:62;
            stp = (gil < 4) ? 5 : 1;
          }
          int kbase = (ls - fo)*32 + qd*8 + j0;
          unsigned short vv[4];
#pragma unroll
          for (int jj = 0; jj < 4; ++jj) {
            int kpp = kbase + jj;
            int h = (kpp >= K5) ? 1 : 0;
            int k = kpp - (h ? K5 : 0);
            int q = (k*205) >> 10;
            int pp = k - q*5;
            int gg = goffB + q;
            int s = c0 + q*stp;
            float a  = bf2f(scb[(p*2 + h)*104 + gg]);
            float xv = bf2f(xpB[(p*68 + s)*4 + pp]);
            float val = (pp < 4) ? a * xv : a;
            if (kpp >= 2*K5) val = 0.f;
            vv[jj] = f2bf(val);
          }
          w2.x = (unsigned)vv[0] | ((unsigned)vv[1] << 16);
          w2.y = (unsigned)vv[2] | ((unsigned)vv[3] << 16);
        }
        *(uint2*)(wpAll + pos) = w2;
      }
    }
    __syncthreads();

    // software-pipelined task loop: issue(i+1) before compute(i)
#pragma unroll
    for (int ii = 0; ii < 6; ++ii) {
      fws_issue(ii*2 + 1, fB, cgB);
      fws_compute(ii*2, fA, cgA);
      if (ii < 5) fws_issue(ii*2 + 2, fA, cgA);
      fws_compute(ii*2 + 1, fB, cgB);
    }
    __syncthreads();
  }

  // ---- C1: ens scores GEMM (M=96 rows (s,p), N=24 (t,h), K=128) ----
#pragma unroll
  for (int ti = 0; ti < 3; ++ti) {
    int T = wave*3 + ti;
    int mtp = T >> 1, ntp = T & 1;
    int rowA = mtp*16 + l15;
    int sx = ((rowA >> 3) ^ rowA) & 7;
    f32x4 acc = {0.f,0.f,0.f,0.f};
#pragma unroll
    for (int kt = 0; kt < 4; ++kt) {
      short8 a = *(const short8*)(outg2 + rowA*128 + (((kt*4 + quad) ^ sx) << 3));
      short8 b = *(const short8*)(qkeB + ((ntp*4 + kt)*64 + lane)*8);
      acc = __builtin_amdgcn_mfma_f32_16x16x32_bf16(a, b, acc, 0, 0, 0);
    }
    int th = ntp*16 + l15;
    if (th < 24) {
      float qb = wsf[QB_ENS + th];
#pragma unroll
      for (int reg = 0; reg < 4; ++reg) {
        int rowE = mtp*16 + quad*4 + reg;
        sce2[((rowE & 7)*24 + th)*16 + (rowE >> 3)] = f2bf((acc[reg] + qb) * 0.125f);
      }
    }
  }
  __syncthreads();

  // ---- C2: softmax over s per (p, t, h) — register-resident ----
  if (tid < 192) {
    unsigned short* row = sce2 + tid*16;
    float ev[12];
    float m = -1e30f;
#pragma unroll
    for (int s = 0; s < 12; ++s) { ev[s] = bf2f(row[s]); m = fmaxf(m, ev[s]); }
    float ssum = 0.f;
#pragma unroll
    for (int s = 0; s < 12; ++s) { float e = __expf(ev[s] - m); ev[s] = e; ssum += e; }
    float inv = 1.f / ssum;
#pragma unroll
    for (int s = 0; s < 12; ++s) row[s] = f2bf(ev[s] * inv);
  }
  __syncthreads();

  // ---- apB: attn weights as B-frags ----
  for (int idx = tid; idx < 4096; idx += 256) {
    int p = idx >> 9, r9 = idx & 511;
    int ln = r9 >> 3, j = r9 & 7;
    int t = ln & 15, qd = ln >> 4;
    int kpp = qd*8 + j;
    int h = kpp >> 4, s = kpp & 15;
    unsigned short v = 0;
    if (s < 12 && t < 12) v = sce2[(p*24 + t*2 + h)*16 + s];
    apB[p*512 + ln*8 + j] = v;
  }
  // preload cens + MeB fragments (reused across all 4 C3 periods)
  float cens0[4], cens1[4];
  {
    float4 c0 = *(const float4*)(wsf + CENS + (wave*2 + 0)*16 + quad*4);
    float4 c1 = *(const float4*)(wsf + CENS + (wave*2 + 1)*16 + quad*4);
    cens0[0]=c0.x; cens0[1]=c0.y; cens0[2]=c0.z; cens0[3]=c0.w;
    cens1[0]=c1.x; cens1[1]=c1.y; cens1[2]=c1.z; cens1[3]=c1.w;
  }
  short8 meAr[16];   // [mi][h][kt]
#pragma unroll
  for (int mi = 0; mi < 2; ++mi)
#pragma unroll
    for (int h = 0; h < 2; ++h)
#pragma unroll
      for (int kt = 0; kt < 4; ++kt)
        meAr[(mi*2 + h)*4 + kt] =
          *(const short8*)(MeB + (((wave*2 + mi)*8 + h*4 + kt)*64 + lane)*8);
  __syncthreads();

  // ---- C3: 2 patches per period: G-GEMM -> R-GEMM -> register LayerNorm ----
  // Gl transpose is intra-wave (each wave writes/reads only rows
  // [wave*32, wave*32+32)) -> no barrier between Gl write and read.
  // stats double-buffered -> single barrier per period.
  for (int pp2 = 0; pp2 < 4; ++pp2) {
    f32x4 g[2][2][2];  // [lp][mi][h]
#pragma unroll
    for (int lp = 0; lp < 2; ++lp)
#pragma unroll
      for (int mi = 0; mi < 2; ++mi)
#pragma unroll
        for (int h = 0; h < 2; ++h) g[lp][mi][h] = (f32x4){0.f,0.f,0.f,0.f};
#pragma unroll
    for (int lp = 0; lp < 2; ++lp) {
      int p = pp2*2 + lp;
      int brow = (l15 < 12) ? (l15*8 + p) : 96;   // shared phantom zero row
      int sx = ((brow >> 3) ^ brow) & 7;
#pragma unroll
      for (int h = 0; h < 2; ++h) {
#pragma unroll
        for (int kt = 0; kt < 4; ++kt) {
          short8 b = *(const short8*)(outg2 + brow*128 + (((kt*4 + quad) ^ sx) << 3));
          g[lp][0][h] = __builtin_amdgcn_mfma_f32_16x16x32_bf16(
              meAr[(0*2 + h)*4 + kt], b, g[lp][0][h], 0, 0, 0);
          g[lp][1][h] = __builtin_amdgcn_mfma_f32_16x16x32_bf16(
              meAr[(1*2 + h)*4 + kt], b, g[lp][1][h], 0, 0, 0);
        }
      }
    }
    // write G to LDS: Gl[lp][r][h*16+s], row stride 40 us (16B-aligned reads)
#pragma unroll
    for (int lp = 0; lp < 2; ++lp)
#pragma unroll
      for (int mi = 0; mi < 2; ++mi)
#pragma unroll
        for (int h = 0; h < 2; ++h)
#pragma unroll
          for (int reg = 0; reg < 4; ++reg) {
            int r = (wave*2 + mi)*16 + quad*4 + reg;
            Gl[lp*5120 + r*40 + h*16 + l15] = f2bf(g[lp][mi][h][reg]);
          }
    // no barrier: intra-wave; compiler orders via lgkmcnt

    // R-GEMM: R[r][t] = G @ a'  (K=32)
    f32x4 rr[2][2];
    float s1[2] = {0.f, 0.f}, s2[2] = {0.f, 0.f};
#pragma unroll
    for (int lp = 0; lp < 2; ++lp) {
      int p = pp2*2 + lp;
      short8 bfrag = *(const short8*)(apB + p*512 + lane*8);
#pragma unroll
      for (int mi = 0; mi < 2; ++mi) {
        int mt2 = wave*2 + mi;
        short8 afrag = *(const short8*)(Gl + lp*5120 + (mt2*16 + l15)*40 + quad*8);
        f32x4 acc = {0.f,0.f,0.f,0.f};
        acc = __builtin_amdgcn_mfma_f32_16x16x32_bf16(afrag, bfrag, acc, 0, 0, 0);
#pragma unroll
        for (int reg = 0; reg < 4; ++reg)
          acc[reg] += (mi ? cens1[reg] : cens0[reg]);
        rr[lp][mi] = acc;
        if (l15 < 12) {
#pragma unroll
          for (int reg = 0; reg < 4; ++reg) {
            float v = acc[reg];
            s1[lp] += v; s2[lp] += v*v;
          }
        }
      }
    }
#pragma unroll
    for (int off = 32; off > 0; off >>= 1) {
#pragma unroll
      for (int lp = 0; lp < 2; ++lp) {
        s1[lp] += __shfl_xor(s1[lp], off);
        s2[lp] += __shfl_xor(s2[lp], off);
      }
    }
    int sb = (pp2 & 1) << 4;               // stats double-buffer
    if (lane == 0) {
#pragma unroll
      for (int lp = 0; lp < 2; ++lp) {
        stats[sb + lp*4 + wave] = s1[lp];
        stats[sb + 8 + lp*4 + wave] = s2[lp];
      }
    }
    __syncthreads();
#pragma unroll
    for (int lp = 0; lp < 2; ++lp) {
      float t1 = stats[sb+lp*4+0] + stats[sb+lp*4+1] + stats[sb+lp*4+2] + stats[sb+lp*4+3];
      float t2 = stats[sb+8+lp*4+0] + stats[sb+8+lp*4+1] + stats[sb+8+lp*4+2] + stats[sb+8+lp*4+3];
      float mean = t1 * (1.f/1536.f);
      float var  = t2 * (1.f/1536.f) - mean*mean;
      float rstd = rsqrtf(var + 1e-5f);
      if (l15 < 12) {
        long nrow = (long)(nbase + pp2*2 + lp) * 1536;
#pragma unroll
        for (int mi = 0; mi < 2; ++mi) {
          int rb = (wave*2 + mi)*16 + quad*4;
          int j = l15*128 + rb;
          float4 gm = *(const float4*)(lgam + j);
          float4 bt = *(const float4*)(lbet + j);
          float4 o;
          o.x = (rr[lp][mi][0] - mean)*rstd*gm.x + bt.x;
          o.y = (rr[lp][mi][1] - mean)*rstd*gm.y + bt.y;
          o.z = (rr[lp][mi][2] - mean)*rstd*gm.z + bt.z;
          o.w = (rr[lp][mi][3] - mean)*rstd*gm.w + bt.w;
          *(float4*)(out + nrow + j) = o;
        }
      }
    }
    // no period-end barrier: stats double-buffered, Gl intra-wave
  }
}

// ---------------------------------------------------------------------------
extern "C" void kernel_launch(void* const* d_in, const int* in_sizes, int n_in,
                              void* d_out, int out_size, void* d_ws, size_t ws_size,
                              hipStream_t stream) {
  const float* x   = (const float*)d_in[0];
  const float* cw  = (const float*)d_in[1];
  const float* cb  = (const float*)d_in[2];
  const float* ce  = (const float*)d_in[3];
  const float* cq  = (const float*)d_in[4];
  const float* giw = (const float*)d_in[5];
  const float* gib = (const float*)d_in[6];
  const float* gow = (const float*)d_in[7];
  const float* gob = (const float*)d_in[8];
  const float* eq  = (const float*)d_in[9];
  const float* eiw = (const float*)d_in[10];
  const float* eib = (const float*)d_in[11];
  const float* eow = (const float*)d_in[12];
  const float* eob = (const float*)d_in[13];
  const float* lg  = (const float*)d_in[14];
  const float* lb  = (const float*)d_in[15];

  float* wsf = (float*)d_ws;
  float* cwq = (float*)((char*)d_ws + CWQ_BYTE);
  float* Mplain = (float*)((char*)d_ws + MPL_BYTE);
  unsigned short* MeB  = (unsigned short*)((char*)d_ws + MEB_BYTE);
  unsigned short* qkeB = (unsigned short*)((char*)d_ws + QKEB_BYTE);
  unsigned short* Fws  = (unsigned short*)((char*)d_ws + FWS_BYTE);

  hwe_p1<<<2204, 256, 0, stream>>>(giw, gib, gow, gob, cq, eq, eiw, eib, eow, eob,
                                   wsf, Mplain, MeB, Fws);
  hwe_p2<<<260, 256, 0, stream>>>(cw, cb, ce, Mplain, wsf, Fws, qkeB, cwq);
  hwe_main<<<1024, 256, 0, stream>>>(x, lg, lb, wsf, cwq, Fws, MeB, qkeB,
                                     (float*)d_out);
}

// Round 3
// 177.608 us; speedup vs baseline: 1.5424x; 1.1550x over previous
//
#include <hip/hip_runtime.h>

// ---------------------------------------------------------------------------
// HieraWeatherEmbedding R10: attack the fixed 131 µs (p1+p2).
//  - p1 Mplain -> MA: same dot products, stored directly as bf16 MFMA
//    A-fragments (layout mirrors proven MeB section). No fp32 round-trip.
//  - p1 new CW2 section (38 blocks): channel-weight matrix as bf16 MFMA
//    B-fragments, computed ONCE (was re-staged by all 192 p2 blocks).
//  - p2 F-build: pure global->MFMA->global. 4 A-frag loads + <=24 B-frag
//    loads + <=24 mfma per block. No LDS, no scalar inner loop.
//  - hwe_main unchanged from R9 (74 µs winner).
// fp32 I/O, bf16 fragments, fp32 accumulate.
// ---------------------------------------------------------------------------

typedef __attribute__((ext_vector_type(8))) short short8;
typedef __attribute__((ext_vector_type(4))) float f32x4;

__constant__ int GOFF[13] = {0,7,14,21,28,35,44,53,62,71,80,97,103};
__constant__ int K5A[12]  = {35,35,35,35,35,45,45,45,45,45,85,30};
__constant__ int SLOTS3[12] = {3,3,3,3,3,3,3,3,3,3,6,2};
__constant__ int FOFFA[12] = {0,3,6,9,12,15,18,21,24,27,30,36};   // slot offsets (total 38)
__constant__ int GSLOT[103] = {
  3,8,13,18,23,28,33,
  4,9,14,19,24,29,34,
  2,7,12,17,22,27,32,
  1,6,11,16,21,26,31,
  0,5,10,15,20,25,30,
  3,8,13,18,23,28,33,38,43,
  4,9,14,19,24,29,34,39,44,
  2,7,12,17,22,27,32,37,42,
  1,6,11,16,21,26,31,36,41,
  0,5,10,15,20,25,30,35,40,
  45,46,47,48,49,50,51,52,53,54,55,56,57,58,59,60,61,
  62,63,64,65,66,67};
__constant__ int GIDX[103] = {
  0,0,0,0,0,0,0, 1,1,1,1,1,1,1, 2,2,2,2,2,2,2, 3,3,3,3,3,3,3, 4,4,4,4,4,4,4,
  5,5,5,5,5,5,5,5,5, 6,6,6,6,6,6,6,6,6, 7,7,7,7,7,7,7,7,7, 8,8,8,8,8,8,8,8,8,
  9,9,9,9,9,9,9,9,9,
  10,10,10,10,10,10,10,10,10,10,10,10,10,10,10,10,10,
  11,11,11,11,11,11};
// tile -> (gi, nt) for the 38 CW2 fragment tiles (prefix sums of SLOTS3 = FOFFA)
__constant__ int TGI[38] = {0,0,0,1,1,1,2,2,2,3,3,3,4,4,4,5,5,5,6,6,6,7,7,7,
                            8,8,8,9,9,9,10,10,10,10,10,10,11,11};
__constant__ int TNT[38] = {0,1,2,0,1,2,0,1,2,0,1,2,0,1,2,0,1,2,0,1,2,0,1,2,
                            0,1,2,0,1,2,0,1,2,3,4,5,0,1};

// compile-time copies for fully-unrolled loops
constexpr int cSLOTS[12] = {3,3,3,3,3,3,3,3,3,3,6,2};
constexpr int cFOFFA[12] = {0,3,6,9,12,15,18,21,24,27,30,36};

// fp32 workspace region (float offsets)
#define QK_GRP 0        // [12][2][128]
#define QK_ENS 3072     // [24][128]
#define QB_GRP 6144     // [12][2]
#define QB_ENS 6176     // [24]
#define CGRP   6208     // [12][128]
#define CENS   7744     // [128]
// byte offsets
#define CWQ_BYTE   43776    // float [103][2][8]
#define MPL_BYTE   50432    // MA: ushort [12][2][8mt][4kt][64][8]  (786432 B)
#define CW2_BYTE   836864   // CW2: ushort [38tile][4kt][64][8]     (155648 B)
#define MEB_BYTE   1623296  // ushort [8mt][8kt][64][8] (65536 B)
#define QKEB_BYTE  1688832  // ushort [2nt][4kt][64][8] (8192 B)
#define FWS_BYTE   1697024  // ushort 304 frags * 512  (311296 B)

__device__ __forceinline__ float bf2f(unsigned short s) {
  return __uint_as_float(((unsigned)s) << 16);
}
__device__ __forceinline__ unsigned short f2bf(float f) {
  unsigned u = __float_as_uint(f);
  u += 0x7fffu + ((u >> 16) & 1u);
  return (unsigned short)(u >> 16);
}

// ---------------------------------------------------------------------------
// P1: QK/QB direct, MA (bf16 A-frags), MeB, CGRP, CENS, CW2 (bf16 B-frags),
// F-zero. Grid 2242 x 256.
// ---------------------------------------------------------------------------
__global__ void hwe_p1(const float* __restrict__ giw, const float* __restrict__ gib,
                       const float* __restrict__ gow, const float* __restrict__ gob,
                       const float* __restrict__ cq,  const float* __restrict__ eq,
                       const float* __restrict__ eiw, const float* __restrict__ eib,
                       const float* __restrict__ eow, const float* __restrict__ eob,
                       const float* __restrict__ cw,  const float* __restrict__ cb,
                       const float* __restrict__ ce,
                       float* __restrict__ wsf, unsigned short* __restrict__ MA,
                       unsigned short* __restrict__ CW2,
                       unsigned short* __restrict__ MeB, unsigned short* __restrict__ Fws) {
  int blk = blockIdx.x, tid = threadIdx.x;
  int wave = tid >> 6, lane = tid & 63;
  if (blk < 48) {                        // QK + QB for (i,h) grp / (t,h) ens
    __shared__ float qf[64];
    bool ens = blk >= 24;
    int bi = ens ? blk - 24 : blk;
    int i = bi >> 1, h = bi & 1;
    const float* W  = ens ? eiw : giw + i*49152;   // [384][128]
    const float* bv = ens ? eib : gib + i*384;     // [384]
    const float* qv = ens ? eq + i*128 : cq + i*128;
    // phase 1: qf[dp] = bv[h*64+dp] + W[h*64+dp][:].qv
    for (int it = 0; it < 16; ++it) {
      int dp = it*4 + wave;
      const float* wrow = W + (h*64 + dp)*128;
      float acc = wrow[lane]*qv[lane] + wrow[lane+64]*qv[lane+64];
#pragma unroll
      for (int off = 32; off > 0; off >>= 1) acc += __shfl_down(acc, off);
      if (lane == 0) qf[dp] = acc + bv[h*64 + dp];
    }
    __syncthreads();
    // phase 2: QK[e] = sum_dp qf[dp]*Wk[dp][e]
    if (tid < 128) {
      int e = tid;
      const float* Wk = W + (128 + h*64)*128 + e;
      float a0=0.f,a1=0.f,a2=0.f,a3=0.f;
      for (int dp = 0; dp < 64; dp += 4) {
        a0 += qf[dp+0] * Wk[(dp+0)*128];
        a1 += qf[dp+1] * Wk[(dp+1)*128];
        a2 += qf[dp+2] * Wk[(dp+2)*128];
        a3 += qf[dp+3] * Wk[(dp+3)*128];
      }
      wsf[(ens ? QK_ENS : QK_GRP) + bi*128 + e] = (a0+a1)+(a2+a3);
    }
    if (wave == 3) {                     // QB = qf . bk
      float acc = qf[lane] * bv[128 + h*64 + lane];
#pragma unroll
      for (int off = 32; off > 0; off >>= 1) acc += __shfl_down(acc, off);
      if (lane == 0) wsf[(ens ? QB_ENS : QB_GRP) + bi] = acc;
    }
  } else if (blk < 1584) {               // MA[gi][h][mt][kt][lane][j] bf16 A-frags
    int b2 = blk - 48;
    int gi = b2 >> 7, r = b2 & 127;
    int ep = tid, h = ep >> 7, e = ep & 127;
    const float* wo = gow + gi*16384 + r*128 + h*64;
    const float* wv = giw + gi*49152 + (256 + h*64)*128 + e;
    float a0=0.f,a1=0.f,a2=0.f,a3=0.f;
    for (int hd = 0; hd < 64; hd += 4) {
      a0 += wo[hd+0] * wv[(hd+0)*128];
      a1 += wo[hd+1] * wv[(hd+1)*128];
      a2 += wo[hd+2] * wv[(hd+2)*128];
      a3 += wo[hd+3] * wv[(hd+3)*128];
    }
    float acc = (a0+a1)+(a2+a3);
    int mt = r >> 4, lr = r & 15, kt = e >> 5, q = (e >> 3) & 3, j = e & 7;
    MA[(((gi*2 + h)*8 + mt)*4 + kt)*512 + (q*16 + lr)*8 + j] = f2bf(acc);
  } else if (blk < 1712) {               // MeB A-frag
    int f2 = (blk - 1584)*256 + tid;
    int r = f2 >> 8, ep = f2 & 255;
    int h = ep >> 7, e = ep & 127;
    const float* wo = eow + r*128 + h*64;
    const float* wv = eiw + (256 + h*64)*128 + e;
    float a0=0.f,a1=0.f,a2=0.f,a3=0.f;
    for (int hd = 0; hd < 64; hd += 4) {
      a0 += wo[hd+0] * wv[(hd+0)*128];
      a1 += wo[hd+1] * wv[(hd+1)*128];
      a2 += wo[hd+2] * wv[(hd+2)*128];
      a3 += wo[hd+3] * wv[(hd+3)*128];
    }
    float acc = (a0+a1)+(a2+a3);
    int mt = r >> 4, lr = r & 15, kt = ep >> 5, q = (ep >> 3) & 3, j = ep & 7;
    MeB[((mt*8 + kt)*64 + (q*16 + lr))*8 + j] = f2bf(acc);
  } else if (blk < 2096) {               // CGRP (1536 wave-tasks)
    int id = (blk - 1712)*4 + wave;
    int i = id >> 7, d = id & 127;
    const float* wrow = gow + i*16384 + d*128;
    const float* bvv = gib + i*384 + 256;
    float acc = wrow[lane]*bvv[lane] + wrow[lane+64]*bvv[lane+64];
#pragma unroll
    for (int off = 32; off > 0; off >>= 1) acc += __shfl_down(acc, off);
    if (lane == 0) wsf[CGRP + id] = acc + gob[i*128 + d];
  } else if (blk < 2128) {               // CENS (128 wave-tasks)
    int d = (blk - 2096)*4 + wave;
    const float* wrow = eow + d*128;
    const float* bvv = eib + 256;
    float acc = wrow[lane]*bvv[lane] + wrow[lane+64]*bvv[lane+64];
#pragma unroll
    for (int off = 32; off > 0; off >>= 1) acc += __shfl_down(acc, off);
    if (lane == 0) wsf[CENS + d] = acc + eob[d];
  } else if (blk < 2166) {               // CW2: one tile per block (38 blocks)
    int tile = blk - 2128;
    int gi = TGI[tile], nt = TNT[tile];
    int kt = tid >> 6;
    int l15b = tid & 15, quadb = (tid >> 4) & 3;
    int k = nt*16 + l15b;
    int e = kt*32 + quadb*8;
    unsigned short vv[8];
    if (k < K5A[gi]) {
      int q = (k*205) >> 10;
      int pp = k - q*5;
      int s = GSLOT[GOFF[gi] + q];
      int v = (s < 45) ? s : s + 20;
      if (pp < 4) {
        const float* src = cw + (v*4 + pp)*128 + e;
#pragma unroll
        for (int j = 0; j < 8; ++j) vv[j] = f2bf(src[j]);
      } else {
        const float* b1 = cb + v*128 + e;
        const float* c1 = ce + v*128 + e;
#pragma unroll
        for (int j = 0; j < 8; ++j) vv[j] = f2bf(b1[j] + c1[j]);
      }
    } else {
#pragma unroll
      for (int j = 0; j < 8; ++j) vv[j] = 0;
    }
    unsigned short* dst = CW2 + (tile*4 + kt)*512 + (tid & 63)*8;
#pragma unroll
    for (int j = 0; j < 8; ++j) dst[j] = vv[j];
  } else {                               // F-zero: 19456 uint4
    int idx = (blk - 2166)*256 + tid;
    if (idx < 19456) ((uint4*)Fws)[idx] = (uint4){0,0,0,0};
  }
}

// ---------------------------------------------------------------------------
// P2: F-build via MFMA (192 blocks, no LDS) + qkeB (16) + cwq (52).
// Grid 260 x 256.
// ---------------------------------------------------------------------------
__global__ void hwe_p2(const float* __restrict__ cw, const float* __restrict__ cb,
                       const float* __restrict__ ce,
                       const unsigned short* __restrict__ MA,
                       const unsigned short* __restrict__ CW2,
                       const float* __restrict__ wsf,
                       unsigned short* __restrict__ Fws,
                       unsigned short* __restrict__ qkeB, float* __restrict__ cwq) {
  int blk = blockIdx.x, tid = threadIdx.x;
  int wave = tid >> 6, lane = tid & 63;
  int quad = lane >> 4, l15 = lane & 15;
  if (blk < 192) {                      // F[rr][k] = sum_e M[rr][e]*c2[k][e]
    int gi = blk >> 4, h = (blk >> 3) & 1, mt = blk & 7;
    int K5 = K5A[gi], S = SLOTS3[gi];
    const unsigned short* MAp = MA + (((gi*2 + h)*8 + mt)*4)*512 + lane*8;
    short8 a[4];
#pragma unroll
    for (int kt = 0; kt < 4; ++kt)
      a[kt] = *(const short8*)(MAp + kt*512);
    for (int nt = wave; nt < S; nt += 4) {     // S == #16-col tiles
      const unsigned short* Bp = CW2 + (FOFFA[gi] + nt)*2048 + lane*8;
      f32x4 acc = {0.f,0.f,0.f,0.f};
#pragma unroll
      for (int kt = 0; kt < 4; ++kt) {
        short8 b = *(const short8*)(Bp + kt*512);
        acc = __builtin_amdgcn_mfma_f32_16x16x32_bf16(a[kt], b, acc, 0, 0, 0);
      }
      int k = nt*16 + l15;                     // D col (N) = l15
      if (k < K5) {
        int kpp = h*K5 + k;
        int base = (FOFFA[gi]*8 + mt*S + (kpp >> 5))*512
                 + ((kpp >> 3) & 3)*128 + (kpp & 7);
#pragma unroll
        for (int reg = 0; reg < 4; ++reg) {
          int rr = quad*4 + reg;               // D row (M)
          Fws[base + rr*8] = f2bf(acc[reg]);
        }
      }
    }
  } else if (blk < 208) {               // qkeB B-frag from QK_ENS
    int f4 = (blk - 192)*256 + tid;     // [0,4096)
    int ln = (f4 >> 3) & 63, j = f4 & 7;
    int th = ((f4 >> 11) & 1)*16 + (ln & 15);
    int kt = (f4 >> 9) & 3;
    float val = (th < 24) ? wsf[QK_ENS + th*128 + kt*32 + (ln >> 4)*8 + j] : 0.f;
    qkeB[f4] = f2bf(val);
  } else {                              // cwq: wave per (gg,h)
    int wid = (blk - 208)*4 + wave;
    if (wid < 206) {
      int gg = wid >> 1, h = wid & 1;
      int gi = GIDX[gg];
      int s = GSLOT[gg];
      int v = (s < 45) ? s : s + 20;
      const float* qk = wsf + QK_GRP + (gi*2 + h)*128;
      float q0 = qk[lane], q1 = qk[lane + 64];
      float a[5];
#pragma unroll
      for (int pp = 0; pp < 4; ++pp)
        a[pp] = cw[(v*4 + pp)*128 + lane]*q0 + cw[(v*4 + pp)*128 + lane + 64]*q1;
      a[4] = (cb[v*128 + lane] + ce[v*128 + lane])*q0 +
             (cb[v*128 + lane + 64] + ce[v*128 + lane + 64])*q1;
#pragma unroll
      for (int off = 32; off > 0; off >>= 1)
#pragma unroll
        for (int kk = 0; kk < 5; ++kk) a[kk] += __shfl_down(a[kk], off);
      if (lane == 0) {
        float* o = cwq + (gg*2 + h)*8;
        o[0] = a[0]*0.125f; o[1] = a[1]*0.125f; o[2] = a[2]*0.125f; o[3] = a[3]*0.125f;
        o[4] = (a[4] + wsf[QB_GRP + gi*2 + h]) * 0.125f;
      }
    }
  }
}

// ---------------------------------------------------------------------------
// Main kernel (unchanged from R9). grid 1024, block 256 (4 waves).
// LDS 53632 B. See R9 comment block for layout.
// ---------------------------------------------------------------------------
__global__ __launch_bounds__(256, 3) void hwe_main(
    const float* __restrict__ x,
    const float* __restrict__ lgam, const float* __restrict__ lbet,
    const float* __restrict__ wsf,  const float* __restrict__ cwq,
    const unsigned short* __restrict__ Fws, const unsigned short* __restrict__ MeB,
    const unsigned short* __restrict__ qkeB,
    float* __restrict__ out) {
  __shared__ __align__(16) unsigned char smem[53632];
  unsigned short* xpB   = (unsigned short*)(smem);
  unsigned short* scb   = (unsigned short*)(smem + 4352);
  unsigned short* wpAll = (unsigned short*)(smem + 7680);
  unsigned short* Gl    = (unsigned short*)(smem);          // C overlay (C3)
  unsigned short* apB   = (unsigned short*)(smem + 20480);  // C overlay
  unsigned short* sce2  = (unsigned short*)(smem);          // C overlay (C1..apB)
  unsigned short* outg2 = (unsigned short*)(smem + 28672);
  float*          stats = (float*)(smem + 53504);           // [2][16]

  const int tid  = threadIdx.x;
  const int wave = tid >> 6;
  const int lane = tid & 63;
  const int quad = lane >> 4;
  const int l15  = lane & 15;

  const int hi   = blockIdx.x >> 4;
  const int wib  = (blockIdx.x & 15) << 3;
  const int nbase = hi*128 + wib;

  // ---- A1: pixels (float2-vectorized) + zero shared phantom row 96 ----
  for (int idx = tid; idx < 1088; idx += 256) {
    int c2 = idx & 7, r = (idx >> 3) & 1, s = idx >> 4;
    int v = (s < 45) ? s : s + 20;
    const float2 xv = *(const float2*)(x + (v*128 + 2*hi + r)*256 + 2*wib + c2*2);
    unsigned pk = (unsigned)f2bf(xv.x) | ((unsigned)f2bf(xv.y) << 16);
    *(unsigned*)(xpB + (c2*68 + s)*4 + r*2) = pk;
  }
  if (tid < 64) ((unsigned*)outg2)[96*64 + tid] = 0u;
  __syncthreads();

  // ---- A2: group scores via cwq fold ----
  for (int idx = tid; idx < 1648; idx += 256) {
    int h = idx & 1, p = (idx >> 1) & 7, gg = idx >> 4;
    int s = GSLOT[gg];
    const float* c = cwq + (gg*2 + h)*8;
    const unsigned short* xr = xpB + (p*68 + s)*4;
    float acc = c[4] + bf2f(xr[0])*c[0] + bf2f(xr[1])*c[1]
                     + bf2f(xr[2])*c[2] + bf2f(xr[3])*c[3];
    scb[(p*2 + h)*104 + gg] = f2bf(acc);
  }
  __syncthreads();

  // ---- A3: softmax per (p,h,group) — register-resident, batched LDS ----
  if (tid < 192) {
    int gi = tid % 12, h = (tid / 12) & 1, p = tid / 24;
    int go = GOFF[gi], G = GOFF[gi+1] - go;
    unsigned short* row = scb + (p*2 + h)*104 + go;
    float ev[17];
    float m = -1e30f;
#pragma unroll
    for (int g = 0; g < 17; ++g) {
      ev[g] = (g < G) ? bf2f(row[g]) : -1e30f;
      m = fmaxf(m, ev[g]);
    }
    float ssum = 0.f;
#pragma unroll
    for (int g = 0; g < 17; ++g) {
      float e = __expf(ev[g] - m);
      ev[g] = e;
      if (g < G) ssum += e;
    }
    float inv = 1.f / ssum;
#pragma unroll
    for (int g = 0; g < 17; ++g)
      if (g < G) row[g] = f2bf(ev[g] * inv);
  }
  __syncthreads();

  // ---- Phase B: two halves of 6 groups; F-folded single GEMM per group ----
#pragma unroll
  for (int hb = 0; hb < 2; ++hb) {
    const int nsl = hb ? 20 : 18;
    const int sbase = hb ? 18 : 0;

    short8 fA[6], fB[6];
    float4 cgA, cgB;
    auto fws_issue = [&](int I, short8 (&buf)[6], float4& cg) {
      int gi = hb*6 + (I >> 1);          // compile-time after unroll
      int S  = cSLOTS[gi];
      int mt = (I & 1)*4 + wave;
      const unsigned short* fp = Fws + (cFOFFA[gi]*8 + mt*S)*512 + lane*8;
#pragma unroll
      for (int kt = 0; kt < 6; ++kt)
        if (kt < S) buf[kt] = *(const short8*)(fp + kt*512);
      cg = *(const float4*)(wsf + CGRP + gi*128 + mt*16 + quad*4);
    };
    auto fws_compute = [&](int I, short8 (&buf)[6], const float4& cg) {
      int gi = hb*6 + (I >> 1);
      int S  = cSLOTS[gi];
      int mt = (I & 1)*4 + wave;
      int lbase = cFOFFA[gi] - sbase;
      f32x4 acc = {0.f,0.f,0.f,0.f};
#pragma unroll
      for (int kt = 0; kt < 6; ++kt)
        if (kt < S) {
          short8 b = *(const short8*)(wpAll + (lbase + kt)*512 + lane*8);
          acc = __builtin_amdgcn_mfma_f32_16x16x32_bf16(buf[kt], b, acc, 0, 0, 0);
        }
      if (l15 < 8) {
        int p = l15;
        int rb = mt*16 + quad*4;
        unsigned short t0 = f2bf(acc[0] + cg.x);
        unsigned short t1 = f2bf(acc[1] + cg.y);
        unsigned short t2 = f2bf(acc[2] + cg.z);
        unsigned short t3 = f2bf(acc[3] + cg.w);
        uint2 w;
        w.x = (unsigned)t0 | ((unsigned)t1 << 16);
        w.y = (unsigned)t2 | ((unsigned)t3 << 16);
        int row = gi*8 + p;
        int ch = (rb >> 3) ^ ((gi ^ p) & 7);      // dual-key swizzle
        *(uint2*)(outg2 + row*128 + ch*8 + (rb & 7)) = w;
      }
    };

    // issue task 0's Fws/CGRP loads: complete under fill + barrier
    fws_issue(0, fA, cgA);

    // ---- fused position-major fill: every wpAll ushort written once ----
    {
      const int nposs = nsl * 512;
      for (int pos = tid*4; pos < nposs; pos += 1024) {
        int pf = (pos >> 3) & 15;
        uint2 w2 = {0u, 0u};
        if (pf < 8) {
          int ls = pos >> 9;
          int qd = (pos >> 7) & 3;
          int j0 = pos & 7;                    // 0 or 4
          int p  = pf;
          int gil, K5, fo, goffB, c0, stp;
          if (hb == 0) {
            gil = (ls>=3)+(ls>=6)+(ls>=9)+(ls>=12)+(ls>=15);
            K5 = (gil < 5) ? 35 : 45;
            fo = gil*3;
            goffB = gil*7;
            c0 = (gil==0)?3:(gil==1)?4:(gil==2)?2:(gil==3)?1:(gil==4)?0:3;
            stp = 5;
          } else {
            gil = (ls>=3)+(ls>=6)+(ls>=9)+(ls>=12)+(ls>=18);
            K5 = (gil < 4) ? 45 : (gil == 4) ? 85 : 30;
            fo = (gil < 5) ? gil*3 : 18;
            goffB = (gil < 5) ? (44 + gil*9) : 97;
            c0 = (gil==0)?4:(gil==1)?2:(gil==2)?1:(gil==3)?0:(gil==4)?45:62;
            stp = (gil < 4) ? 5 : 1;
          }
          int kbase = (ls - fo)*32 + qd*8 + j0;
          unsigned short vv[4];
#pragma unroll
          for (int jj = 0; jj < 4; ++jj) {
            int kpp = kbase + jj;
            int h = (kpp >= K5) ? 1 : 0;
            int k = kpp - (h ? K5 : 0);
            int q = (k*205) >> 10;
            int pp = k - q*5;
            int gg = goffB + q;
            int s = c0 + q*stp;
            float a  = bf2f(scb[(p*2 + h)*104 + gg]);
            float xv = bf2f(xpB[(p*68 + s)*4 + pp]);
            float val = (pp < 4) ? a * xv : a;
            if (kpp >= 2*K5) val = 0.f;
            vv[jj] = f2bf(val);
          }
          w2.x = (unsigned)vv[0] | ((unsigned)vv[1] << 16);
          w2.y = (unsigned)vv[2] | ((unsigned)vv[3] << 16);
        }
        *(uint2*)(wpAll + pos) = w2;
      }
    }
    __syncthreads();

    // software-pipelined task loop: issue(i+1) before compute(i)
#pragma unroll
    for (int ii = 0; ii < 6; ++ii) {
      fws_issue(ii*2 + 1, fB, cgB);
      fws_compute(ii*2, fA, cgA);
      if (ii < 5) fws_issue(ii*2 + 2, fA, cgA);
      fws_compute(ii*2 + 1, fB, cgB);
    }
    __syncthreads();
  }

  // ---- C1: ens scores GEMM (M=96 rows (s,p), N=24 (t,h), K=128) ----
#pragma unroll
  for (int ti = 0; ti < 3; ++ti) {
    int T = wave*3 + ti;
    int mtp = T >> 1, ntp = T & 1;
    int rowA = mtp*16 + l15;
    int sx = ((rowA >> 3) ^ rowA) & 7;
    f32x4 acc = {0.f,0.f,0.f,0.f};
#pragma unroll
    for (int kt = 0; kt < 4; ++kt) {
      short8 a = *(const short8*)(outg2 + rowA*128 + (((kt*4 + quad) ^ sx) << 3));
      short8 b = *(const short8*)(qkeB + ((ntp*4 + kt)*64 + lane)*8);
      acc = __builtin_amdgcn_mfma_f32_16x16x32_bf16(a, b, acc, 0, 0, 0);
    }
    int th = ntp*16 + l15;
    if (th < 24) {
      float qb = wsf[QB_ENS + th];
#pragma unroll
      for (int reg = 0; reg < 4; ++reg) {
        int rowE = mtp*16 + quad*4 + reg;
        sce2[((rowE & 7)*24 + th)*16 + (rowE >> 3)] = f2bf((acc[reg] + qb) * 0.125f);
      }
    }
  }
  __syncthreads();

  // ---- C2: softmax over s per (p, t, h) — register-resident ----
  if (tid < 192) {
    unsigned short* row = sce2 + tid*16;
    float ev[12];
    float m = -1e30f;
#pragma unroll
    for (int s = 0; s < 12; ++s) { ev[s] = bf2f(row[s]); m = fmaxf(m, ev[s]); }
    float ssum = 0.f;
#pragma unroll
    for (int s = 0; s < 12; ++s) { float e = __expf(ev[s] - m); ev[s] = e; ssum += e; }
    float inv = 1.f / ssum;
#pragma unroll
    for (int s = 0; s < 12; ++s) row[s] = f2bf(ev[s] * inv);
  }
  __syncthreads();

  // ---- apB: attn weights as B-frags ----
  for (int idx = tid; idx < 4096; idx += 256) {
    int p = idx >> 9, r9 = idx & 511;
    int ln = r9 >> 3, j = r9 & 7;
    int t = ln & 15, qd = ln >> 4;
    int kpp = qd*8 + j;
    int h = kpp >> 4, s = kpp & 15;
    unsigned short v = 0;
    if (s < 12 && t < 12) v = sce2[(p*24 + t*2 + h)*16 + s];
    apB[p*512 + ln*8 + j] = v;
  }
  // preload cens + MeB fragments (reused across all 4 C3 periods)
  float cens0[4], cens1[4];
  {
    float4 c0 = *(const float4*)(wsf + CENS + (wave*2 + 0)*16 + quad*4);
    float4 c1 = *(const float4*)(wsf + CENS + (wave*2 + 1)*16 + quad*4);
    cens0[0]=c0.x; cens0[1]=c0.y; cens0[2]=c0.z; cens0[3]=c0.w;
    cens1[0]=c1.x; cens1[1]=c1.y; cens1[2]=c1.z; cens1[3]=c1.w;
  }
  short8 meAr[16];   // [mi][h][kt]
#pragma unroll
  for (int mi = 0; mi < 2; ++mi)
#pragma unroll
    for (int h = 0; h < 2; ++h)
#pragma unroll
      for (int kt = 0; kt < 4; ++kt)
        meAr[(mi*2 + h)*4 + kt] =
          *(const short8*)(MeB + (((wave*2 + mi)*8 + h*4 + kt)*64 + lane)*8);
  __syncthreads();

  // ---- C3: 2 patches per period: G-GEMM -> R-GEMM -> register LayerNorm ----
  for (int pp2 = 0; pp2 < 4; ++pp2) {
    f32x4 g[2][2][2];  // [lp][mi][h]
#pragma unroll
    for (int lp = 0; lp < 2; ++lp)
#pragma unroll
      for (int mi = 0; mi < 2; ++mi)
#pragma unroll
        for (int h = 0; h < 2; ++h) g[lp][mi][h] = (f32x4){0.f,0.f,0.f,0.f};
#pragma unroll
    for (int lp = 0; lp < 2; ++lp) {
      int p = pp2*2 + lp;
      int brow = (l15 < 12) ? (l15*8 + p) : 96;   // shared phantom zero row
      int sx = ((brow >> 3) ^ brow) & 7;
#pragma unroll
      for (int h = 0; h < 2; ++h) {
#pragma unroll
        for (int kt = 0; kt < 4; ++kt) {
          short8 b = *(const short8*)(outg2 + brow*128 + (((kt*4 + quad) ^ sx) << 3));
          g[lp][0][h] = __builtin_amdgcn_mfma_f32_16x16x32_bf16(
              meAr[(0*2 + h)*4 + kt], b, g[lp][0][h], 0, 0, 0);
          g[lp][1][h] = __builtin_amdgcn_mfma_f32_16x16x32_bf16(
              meAr[(1*2 + h)*4 + kt], b, g[lp][1][h], 0, 0, 0);
        }
      }
    }
    // write G to LDS: Gl[lp][r][h*16+s], row stride 40 us (16B-aligned reads)
#pragma unroll
    for (int lp = 0; lp < 2; ++lp)
#pragma unroll
      for (int mi = 0; mi < 2; ++mi)
#pragma unroll
        for (int h = 0; h < 2; ++h)
#pragma unroll
          for (int reg = 0; reg < 4; ++reg) {
            int r = (wave*2 + mi)*16 + quad*4 + reg;
            Gl[lp*5120 + r*40 + h*16 + l15] = f2bf(g[lp][mi][h][reg]);
          }
    // no barrier: intra-wave; compiler orders via lgkmcnt

    // R-GEMM: R[r][t] = G @ a'  (K=32)
    f32x4 rr[2][2];
    float s1[2] = {0.f, 0.f}, s2[2] = {0.f, 0.f};
#pragma unroll
    for (int lp = 0; lp < 2; ++lp) {
      int p = pp2*2 + lp;
      short8 bfrag = *(const short8*)(apB + p*512 + lane*8);
#pragma unroll
      for (int mi = 0; mi < 2; ++mi) {
        int mt2 = wave*2 + mi;
        short8 afrag = *(const short8*)(Gl + lp*5120 + (mt2*16 + l15)*40 + quad*8);
        f32x4 acc = {0.f,0.f,0.f,0.f};
        acc = __builtin_amdgcn_mfma_f32_16x16x32_bf16(afrag, bfrag, acc, 0, 0, 0);
#pragma unroll
        for (int reg = 0; reg < 4; ++reg)
          acc[reg] += (mi ? cens1[reg] : cens0[reg]);
        rr[lp][mi] = acc;
        if (l15 < 12) {
#pragma unroll
          for (int reg = 0; reg < 4; ++reg) {
            float v = acc[reg];
            s1[lp] += v; s2[lp] += v*v;
          }
        }
      }
    }
#pragma unroll
    for (int off = 32; off > 0; off >>= 1) {
#pragma unroll
      for (int lp = 0; lp < 2; ++lp) {
        s1[lp] += __shfl_xor(s1[lp], off);
        s2[lp] += __shfl_xor(s2[lp], off);
      }
    }
    int sb = (pp2 & 1) << 4;               // stats double-buffer
    if (lane == 0) {
#pragma unroll
      for (int lp = 0; lp < 2; ++lp) {
        stats[sb + lp*4 + wave] = s1[lp];
        stats[sb + 8 + lp*4 + wave] = s2[lp];
      }
    }
    __syncthreads();
#pragma unroll
    for (int lp = 0; lp < 2; ++lp) {
      float t1 = stats[sb+lp*4+0] + stats[sb+lp*4+1] + stats[sb+lp*4+2] + stats[sb+lp*4+3];
      float t2 = stats[sb+8+lp*4+0] + stats[sb+8+lp*4+1] + stats[sb+8+lp*4+2] + stats[sb+8+lp*4+3];
      float mean = t1 * (1.f/1536.f);
      float var  = t2 * (1.f/1536.f) - mean*mean;
      float rstd = rsqrtf(var + 1e-5f);
      if (l15 < 12) {
        long nrow = (long)(nbase + pp2*2 + lp) * 1536;
#pragma unroll
        for (int mi = 0; mi < 2; ++mi) {
          int rb = (wave*2 + mi)*16 + quad*4;
          int j = l15*128 + rb;
          float4 gm = *(const float4*)(lgam + j);
          float4 bt = *(const float4*)(lbet + j);
          float4 o;
          o.x = (rr[lp][mi][0] - mean)*rstd*gm.x + bt.x;
          o.y = (rr[lp][mi][1] - mean)*rstd*gm.y + bt.y;
          o.z = (rr[lp][mi][2] - mean)*rstd*gm.z + bt.z;
          o.w = (rr[lp][mi][3] - mean)*rstd*gm.w + bt.w;
          *(float4*)(out + nrow + j) = o;
        }
      }
    }
    // no period-end barrier: stats double-buffered, Gl intra-wave
  }
}

// ---------------------------------------------------------------------------
extern "C" void kernel_launch(void* const* d_in, const int* in_sizes, int n_in,
                              void* d_out, int out_size, void* d_ws, size_t ws_size,
                              hipStream_t stream) {
  const float* x   = (const float*)d_in[0];
  const float* cw  = (const float*)d_in[1];
  const float* cb  = (const float*)d_in[2];
  const float* ce  = (const float*)d_in[3];
  const float* cq  = (const float*)d_in[4];
  const float* giw = (const float*)d_in[5];
  const float* gib = (const float*)d_in[6];
  const float* gow = (const float*)d_in[7];
  const float* gob = (const float*)d_in[8];
  const float* eq  = (const float*)d_in[9];
  const float* eiw = (const float*)d_in[10];
  const float* eib = (const float*)d_in[11];
  const float* eow = (const float*)d_in[12];
  const float* eob = (const float*)d_in[13];
  const float* lg  = (const float*)d_in[14];
  const float* lb  = (const float*)d_in[15];

  float* wsf = (float*)d_ws;
  float* cwq = (float*)((char*)d_ws + CWQ_BYTE);
  unsigned short* MA   = (unsigned short*)((char*)d_ws + MPL_BYTE);
  unsigned short* CW2  = (unsigned short*)((char*)d_ws + CW2_BYTE);
  unsigned short* MeB  = (unsigned short*)((char*)d_ws + MEB_BYTE);
  unsigned short* qkeB = (unsigned short*)((char*)d_ws + QKEB_BYTE);
  unsigned short* Fws  = (unsigned short*)((char*)d_ws + FWS_BYTE);

  hwe_p1<<<2242, 256, 0, stream>>>(giw, gib, gow, gob, cq, eq, eiw, eib, eow, eob,
                                   cw, cb, ce, wsf, MA, CW2, MeB, Fws);
  hwe_p2<<<260, 256, 0, stream>>>(cw, cb, ce, MA, CW2, wsf, Fws, qkeB, cwq);
  hwe_main<<<1024, 256, 0, stream>>>(x, lg, lb, wsf, cwq, Fws, MeB, qkeB,
                                     (float*)d_out);
}